// Round 1
// baseline (3597.025 us; speedup 1.0000x reference)
//
#include <hip/hip_runtime.h>
#include <hip/hip_bf16.h>
#include <math.h>

// Problem constants
#define B_ 4
#define L_ 512
#define DM 768
#define E_ 1536
#define N_ 16
#define R_ 48
#define K_ 4
#define NL_ 4
#define H_ 1536
#define T_ 28
#define BT_ (B_ * L_)   // 2048 tokens

__device__ __forceinline__ float sigmoidf_(float v) { return 1.0f / (1.0f + expf(-v)); }
__device__ __forceinline__ float siluf_(float v) { return v * sigmoidf_(v); }
__device__ __forceinline__ float softplusf_(float v) {
    return fmaxf(v, 0.0f) + log1pf(expf(-fabsf(v)));
}

// ---------------- embed gather: h[bt,:] = embed[ids[bt],:] ----------------
__global__ __launch_bounds__(256) void k_embed(const int* __restrict__ ids,
                                               const float* __restrict__ embed,
                                               float* __restrict__ h) {
    int bt = blockIdx.x;
    int tok = ids[bt];
    const float* src = embed + (size_t)tok * DM;
    float* dst = h + (size_t)bt * DM;
    for (int c = threadIdx.x; c < DM; c += 256) dst[c] = src[c];
}

// ---------------- RMSNorm (row per block, D=768, 3 elems/thread) ----------------
__global__ __launch_bounds__(256) void k_rmsnorm(const float* __restrict__ base, long rstride,
                                                 const float* __restrict__ w,
                                                 float* __restrict__ out, long ostride) {
    int tid = threadIdx.x;
    const float* row = base + (size_t)blockIdx.x * rstride;
    float v0 = row[tid], v1 = row[tid + 256], v2 = row[tid + 512];
    float s = v0 * v0 + v1 * v1 + v2 * v2;
#pragma unroll
    for (int m = 1; m < 64; m <<= 1) s += __shfl_xor(s, m);
    __shared__ float red[4];
    if ((tid & 63) == 0) red[tid >> 6] = s;
    __syncthreads();
    s = red[0] + red[1] + red[2] + red[3];
    float rs = rsqrtf(s * (1.0f / (float)DM) + 1e-5f);
    float* orow = out + (size_t)blockIdx.x * ostride;
    orow[tid]       = v0 * rs * w[tid];
    orow[tid + 256] = v1 * rs * w[tid + 256];
    orow[tid + 512] = v2 * rs * w[tid + 512];
}

// ---------------- f32 GEMM: C[M,N] = A[M,K] @ B[K,N] (+= if ACCUM) ----------------
// 64x64 tile, BK=16, 256 threads, 4x4 per-thread microtile, float4 LDS loads.
#define GBM 64
#define GBN 64
#define GBK 16
template <bool ACCUM>
__global__ __launch_bounds__(256) void k_gemm(const float* __restrict__ A,
                                              const float* __restrict__ Bm,
                                              float* __restrict__ C,
                                              int M, int N, int K) {
    __shared__ float As[GBK][GBM + 4];
    __shared__ float Bs[GBK][GBN + 4];
    int tid = threadIdx.x;
    int tx = tid & 15;   // n
    int ty = tid >> 4;   // m
    int m0 = blockIdx.y * GBM;
    int n0 = blockIdx.x * GBN;

    float acc[4][4] = {};

    for (int k0 = 0; k0 < K; k0 += GBK) {
        // A tile 64x16: one float4 per thread along K
        {
            int m = tid >> 2;
            int kq = tid & 3;
            float4 a4 = *(const float4*)(A + (size_t)(m0 + m) * K + k0 + kq * 4);
            As[kq * 4 + 0][m] = a4.x;
            As[kq * 4 + 1][m] = a4.y;
            As[kq * 4 + 2][m] = a4.z;
            As[kq * 4 + 3][m] = a4.w;
        }
        // B tile 16x64: one float4 per thread along N (coalesced)
        {
            int kk = tid >> 4;
            int nq = tid & 15;
            float4 b4 = *(const float4*)(Bm + (size_t)(k0 + kk) * N + n0 + nq * 4);
            *(float4*)&Bs[kk][nq * 4] = b4;
        }
        __syncthreads();
#pragma unroll
        for (int kk = 0; kk < GBK; ++kk) {
            float4 av = *(const float4*)&As[kk][ty * 4];
            float4 bv = *(const float4*)&Bs[kk][tx * 4];
            float a[4] = {av.x, av.y, av.z, av.w};
            float b[4] = {bv.x, bv.y, bv.z, bv.w};
#pragma unroll
            for (int i = 0; i < 4; ++i)
#pragma unroll
                for (int j = 0; j < 4; ++j) acc[i][j] += a[i] * b[j];
        }
        __syncthreads();
    }
#pragma unroll
    for (int i = 0; i < 4; ++i) {
        float* crow = C + (size_t)(m0 + ty * 4 + i) * N + n0 + tx * 4;
        float4 cv = make_float4(acc[i][0], acc[i][1], acc[i][2], acc[i][3]);
        if (ACCUM) {
            float4 old = *(float4*)crow;
            cv.x += old.x; cv.y += old.y; cv.z += old.z; cv.w += old.w;
        }
        *(float4*)crow = cv;
    }
}

// ---------------- causal depthwise conv (K=4) + SiLU; reads x-half of xz ----------------
__global__ __launch_bounds__(256) void k_conv(const float* __restrict__ xz,
                                              const float* __restrict__ cw,
                                              const float* __restrict__ cb,
                                              float* __restrict__ xc) {
    int idx = blockIdx.x * 256 + threadIdx.x;  // < BT_*E_
    int e = idx % E_;
    int bt = idx / E_;
    int t = bt & (L_ - 1);
    const float* base = xz + (size_t)bt * (2 * E_) + e;
    float w0 = cw[e * 4 + 0], w1 = cw[e * 4 + 1], w2 = cw[e * 4 + 2], w3 = cw[e * 4 + 3];
    float acc = cb[e] + base[0] * w3;
    if (t >= 1) acc += base[-(2 * E_)] * w2;
    if (t >= 2) acc += base[-(4 * E_)] * w1;
    if (t >= 3) acc += base[-(6 * E_)] * w0;
    xc[idx] = siluf_(acc);
}

// ---------------- x_proj: proj[bt,0:80] = xc[bt,:] @ w[1536,80], 4 tokens/block ----------------
__global__ __launch_bounds__(128) void k_xproj(const float* __restrict__ xc,
                                               const float* __restrict__ w,
                                               float* __restrict__ proj) {
    __shared__ float xr[4][E_];
    int bt0 = blockIdx.x * 4;
    for (int c = threadIdx.x; c < 4 * E_; c += 128)
        ((float*)xr)[c] = xc[(size_t)bt0 * E_ + c];
    __syncthreads();
    int j = threadIdx.x;
    if (j < (R_ + 2 * N_)) {
        float a0 = 0, a1 = 0, a2 = 0, a3 = 0;
#pragma unroll 4
        for (int k = 0; k < E_; ++k) {
            float wv = w[k * (R_ + 2 * N_) + j];
            a0 += xr[0][k] * wv;
            a1 += xr[1][k] * wv;
            a2 += xr[2][k] * wv;
            a3 += xr[3][k] * wv;
        }
        proj[(size_t)(bt0 + 0) * 80 + j] = a0;
        proj[(size_t)(bt0 + 1) * 80 + j] = a1;
        proj[(size_t)(bt0 + 2) * 80 + j] = a2;
        proj[(size_t)(bt0 + 3) * 80 + j] = a3;
    }
}

// ---------------- dt: dt[bt,e] = softplus(proj[bt,0:48] @ dw[48,1536] + db), 4 tokens/block ----------------
__global__ __launch_bounds__(256) void k_dt(const float* __restrict__ proj,
                                            const float* __restrict__ dw,
                                            const float* __restrict__ db,
                                            float* __restrict__ dt) {
    __shared__ float pr[4][R_];
    int bt0 = blockIdx.x * 4;
    if (threadIdx.x < 4 * R_)
        pr[threadIdx.x / R_][threadIdx.x % R_] =
            proj[(size_t)(bt0 + threadIdx.x / R_) * 80 + (threadIdx.x % R_)];
    __syncthreads();
#pragma unroll
    for (int rr = 0; rr < 6; ++rr) {
        int e = threadIdx.x + rr * 256;
        float bv = db[e];
        float a0 = bv, a1 = bv, a2 = bv, a3 = bv;
#pragma unroll 4
        for (int k = 0; k < R_; ++k) {
            float wv = dw[k * E_ + e];
            a0 += pr[0][k] * wv;
            a1 += pr[1][k] * wv;
            a2 += pr[2][k] * wv;
            a3 += pr[3][k] * wv;
        }
        dt[(size_t)(bt0 + 0) * E_ + e] = softplusf_(a0);
        dt[(size_t)(bt0 + 1) * E_ + e] = softplusf_(a1);
        dt[(size_t)(bt0 + 2) * E_ + e] = softplusf_(a2);
        dt[(size_t)(bt0 + 3) * E_ + e] = softplusf_(a3);
    }
}

// ---------------- selective scan: 16 lanes per (b,e); fused y*silu(z) output ----------------
__global__ __launch_bounds__(256) void k_scan(const float* __restrict__ xc,
                                              const float* __restrict__ dt,
                                              const float* __restrict__ proj,
                                              const float* __restrict__ xz,
                                              const float* __restrict__ A_log,
                                              const float* __restrict__ Dp,
                                              float* __restrict__ yz) {
    int g = blockIdx.x * 16 + (threadIdx.x >> 4);  // [0, B_*E_)
    int n = threadIdx.x & 15;
    int b = g / E_;
    int e = g - b * E_;
    float A = -expf(A_log[e * N_ + n]);
    float dpe = Dp[e];

    size_t rbase = (size_t)b * L_ * E_ + e;         // dt/xc/yz: + t*E_
    size_t pbase = (size_t)b * L_ * 80;             // proj: + t*80
    size_t zbase = (size_t)b * L_ * (2 * E_) + E_ + e;  // z half of xz: + t*2E_

    float hst = 0.0f;
    float dtv = dt[rbase], xv = xc[rbase];
    float Bv = proj[pbase + R_ + n], Cv = proj[pbase + R_ + N_ + n];
    float zv = xz[zbase];

    for (int t = 0; t < L_; ++t) {
        float dtn = 0, xn = 0, Bn = 0, Cn = 0, zn = 0;
        if (t < L_ - 1) {
            size_t r2 = rbase + (size_t)(t + 1) * E_;
            dtn = dt[r2];
            xn = xc[r2];
            size_t p2 = pbase + (size_t)(t + 1) * 80;
            Bn = proj[p2 + R_ + n];
            Cn = proj[p2 + R_ + N_ + n];
            zn = xz[zbase + (size_t)(t + 1) * (2 * E_)];
        }
        float dA = expf(dtv * A);
        hst = dA * hst + (dtv * xv) * Bv;
        float p = hst * Cv;
        p += __shfl_xor(p, 1);
        p += __shfl_xor(p, 2);
        p += __shfl_xor(p, 4);
        p += __shfl_xor(p, 8);
        float y = p + xv * dpe;
        float outv = y * siluf_(zv);
        if (n == 0) yz[rbase + (size_t)t * E_] = outv;
        dtv = dtn; xv = xn; Bv = Bn; Cv = Cn; zv = zn;
    }
}

// ---------------- head: hrel[b,:] = relu(cls[b,:] @ top_w + top_b) ----------------
__global__ __launch_bounds__(256) void k_top(const float* __restrict__ cls,
                                             const float* __restrict__ w,
                                             const float* __restrict__ bias,
                                             float* __restrict__ hrel) {
    __shared__ float xr[DM];
    int b = blockIdx.x;
    for (int c = threadIdx.x; c < DM; c += 256) xr[c] = cls[(size_t)b * DM + c];
    __syncthreads();
#pragma unroll
    for (int rr = 0; rr < H_ / 256; ++rr) {
        int j = threadIdx.x + rr * 256;
        float acc = bias[j];
#pragma unroll 4
        for (int k = 0; k < DM; ++k) acc += xr[k] * w[k * H_ + j];
        hrel[(size_t)b * H_ + j] = fmaxf(acc, 0.0f);
    }
}

// ---------------- head: out[b,t] = hrel[b,:] @ bot_w + bot_b ----------------
__global__ __launch_bounds__(128) void k_bot(const float* __restrict__ hrel,
                                             const float* __restrict__ w,
                                             const float* __restrict__ bias,
                                             float* __restrict__ out) {
    int tid = threadIdx.x;
    if (tid < B_ * T_) {
        int b = tid / T_, j = tid % T_;
        float acc = bias[j];
#pragma unroll 4
        for (int k = 0; k < H_; ++k) acc += hrel[(size_t)b * H_ + k] * w[k * T_ + j];
        out[(size_t)b * T_ + j] = acc;
    }
}

extern "C" void kernel_launch(void* const* d_in, const int* in_sizes, int n_in,
                              void* d_out, int out_size, void* d_ws, size_t ws_size,
                              hipStream_t stream) {
    const int*   ids       = (const int*)d_in[0];
    const float* embed     = (const float*)d_in[1];
    const float* in_proj_w = (const float*)d_in[2];
    const float* conv_w    = (const float*)d_in[3];
    const float* conv_b    = (const float*)d_in[4];
    const float* x_proj_w  = (const float*)d_in[5];
    const float* dt_w      = (const float*)d_in[6];
    const float* dt_b      = (const float*)d_in[7];
    const float* A_log     = (const float*)d_in[8];
    const float* D_p       = (const float*)d_in[9];
    const float* out_w     = (const float*)d_in[10];
    const float* norm_w    = (const float*)d_in[11];
    const float* norm_f_w  = (const float*)d_in[12];
    const float* top_w     = (const float*)d_in[13];
    const float* top_b     = (const float*)d_in[14];
    const float* bot_w     = (const float*)d_in[15];
    const float* bot_b     = (const float*)d_in[16];
    float* out = (float*)d_out;

    // workspace layout (floats)
    float* ws = (float*)d_ws;
    float* h    = ws;                       // 2048*768
    float* xi   = h + (size_t)BT_ * DM;     // 2048*768
    float* xz   = xi + (size_t)BT_ * DM;    // 2048*3072
    float* xc   = xz + (size_t)BT_ * 2 * E_; // 2048*1536
    float* proj = xc + (size_t)BT_ * E_;    // 2048*80
    float* dtb  = proj + (size_t)BT_ * 80;  // 2048*1536
    float* yz   = dtb + (size_t)BT_ * E_;   // 2048*1536
    float* cls  = yz + (size_t)BT_ * E_;    // 4*768
    float* hrel = cls + (size_t)B_ * DM;    // 4*1536

    k_embed<<<BT_, 256, 0, stream>>>(ids, embed, h);

    for (int i = 0; i < NL_; ++i) {
        const float* ipw = in_proj_w + (size_t)i * DM * 2 * E_;
        const float* cwi = conv_w + (size_t)i * E_ * K_;
        const float* cbi = conv_b + (size_t)i * E_;
        const float* xpw = x_proj_w + (size_t)i * E_ * (R_ + 2 * N_);
        const float* dwi = dt_w + (size_t)i * R_ * E_;
        const float* dbi = dt_b + (size_t)i * E_;
        const float* ali = A_log + (size_t)i * E_ * N_;
        const float* dpi = D_p + (size_t)i * E_;
        const float* owi = out_w + (size_t)i * E_ * DM;
        const float* nwi = norm_w + (size_t)i * DM;

        k_rmsnorm<<<BT_, 256, 0, stream>>>(h, DM, nwi, xi, DM);
        k_gemm<false><<<dim3(2 * E_ / GBN, BT_ / GBM), 256, 0, stream>>>(
            xi, ipw, xz, BT_, 2 * E_, DM);
        k_conv<<<BT_ * E_ / 256, 256, 0, stream>>>(xz, cwi, cbi, xc);
        k_xproj<<<BT_ / 4, 128, 0, stream>>>(xc, xpw, proj);
        k_dt<<<BT_ / 4, 256, 0, stream>>>(proj, dwi, dbi, dtb);
        k_scan<<<B_ * E_ / 16, 256, 0, stream>>>(xc, dtb, proj, xz, ali, dpi, yz);
        k_gemm<true><<<dim3(DM / GBN, BT_ / GBM), 256, 0, stream>>>(
            yz, owi, h, BT_, DM, E_);
    }

    // final rmsnorm only on last token of each batch (only cls is consumed)
    k_rmsnorm<<<B_, 256, 0, stream>>>(h + (size_t)(L_ - 1) * DM, (long)L_ * DM,
                                      norm_f_w, cls, DM);
    k_top<<<B_, 256, 0, stream>>>(cls, top_w, top_b, hrel);
    k_bot<<<1, 128, 0, stream>>>(hrel, bot_w, bot_b, out);
}

// Round 2
// 3193.513 us; speedup vs baseline: 1.1264x; 1.1264x over previous
//
#include <hip/hip_runtime.h>
#include <hip/hip_bf16.h>
#include <math.h>

// Problem constants
#define B_ 4
#define L_ 512
#define DM 768
#define E_ 1536
#define N_ 16
#define R_ 48
#define K_ 4
#define NL_ 4
#define H_ 1536
#define T_ 28
#define BT_ (B_ * L_)   // 2048 tokens

__device__ __forceinline__ float sigmoidf_(float v) { return 1.0f / (1.0f + expf(-v)); }
__device__ __forceinline__ float siluf_(float v) { return v * sigmoidf_(v); }
__device__ __forceinline__ float softplusf_(float v) {
    return fmaxf(v, 0.0f) + log1pf(expf(-fabsf(v)));
}

// ---------------- embed gather ----------------
__global__ __launch_bounds__(256) void k_embed(const int* __restrict__ ids,
                                               const float* __restrict__ embed,
                                               float* __restrict__ h) {
    int bt = blockIdx.x;
    int tok = ids[bt];
    const float* src = embed + (size_t)tok * DM;
    float* dst = h + (size_t)bt * DM;
    for (int c = threadIdx.x; c < DM; c += 256) dst[c] = src[c];
}

// ---------------- RMSNorm (row per block, D=768) ----------------
__global__ __launch_bounds__(256) void k_rmsnorm(const float* __restrict__ base, long rstride,
                                                 const float* __restrict__ w,
                                                 float* __restrict__ out, long ostride) {
    int tid = threadIdx.x;
    const float* row = base + (size_t)blockIdx.x * rstride;
    float v0 = row[tid], v1 = row[tid + 256], v2 = row[tid + 512];
    float s = v0 * v0 + v1 * v1 + v2 * v2;
#pragma unroll
    for (int m = 1; m < 64; m <<= 1) s += __shfl_xor(s, m);
    __shared__ float red[4];
    if ((tid & 63) == 0) red[tid >> 6] = s;
    __syncthreads();
    s = red[0] + red[1] + red[2] + red[3];
    float rs = rsqrtf(s * (1.0f / (float)DM) + 1e-5f);
    float* orow = out + (size_t)blockIdx.x * ostride;
    orow[tid]       = v0 * rs * w[tid];
    orow[tid + 256] = v1 * rs * w[tid + 256];
    orow[tid + 512] = v2 * rs * w[tid + 512];
}

// ---------------- f32 GEMM: C[M,N] = A[M,K] @ B[K,N] (+= if ACCUM) ----------------
// Templated BMxBN tile, BK=16, 256 threads (16x16), TMxTN per-thread microtile.
#define GBK 16
template <int BM, int BN, int TM, int TN, bool ACCUM>
__global__ __launch_bounds__(256) void k_gemm(const float* __restrict__ A,
                                              const float* __restrict__ Bm,
                                              float* __restrict__ C,
                                              int M, int N, int K) {
    __shared__ float As[GBK][BM + 4];
    __shared__ float Bs[GBK][BN + 4];
    int tid = threadIdx.x;
    int tx = tid & 15;   // n
    int ty = tid >> 4;   // m
    int m0 = blockIdx.y * BM;
    int n0 = blockIdx.x * BN;

    float acc[TM][TN] = {};

    constexpr int QA = BM / 64;  // float4 loads of A per thread
    constexpr int QB = BN / 64;  // float4 loads of B per thread

    for (int k0 = 0; k0 < K; k0 += GBK) {
        // A tile BM x 16, store transposed into As[k][m]
#pragma unroll
        for (int i = 0; i < QA; ++i) {
            int idx = tid + i * 256;          // quad index
            int m = idx >> 2;
            int kq = idx & 3;
            float4 a4 = *(const float4*)(A + (size_t)(m0 + m) * K + k0 + kq * 4);
            As[kq * 4 + 0][m] = a4.x;
            As[kq * 4 + 1][m] = a4.y;
            As[kq * 4 + 2][m] = a4.z;
            As[kq * 4 + 3][m] = a4.w;
        }
        // B tile 16 x BN (coalesced rows)
#pragma unroll
        for (int i = 0; i < QB; ++i) {
            int idx = tid + i * 256;
            int kk = idx / (BN / 4);
            int nq = idx % (BN / 4);
            float4 b4 = *(const float4*)(Bm + (size_t)(k0 + kk) * N + n0 + nq * 4);
            *(float4*)&Bs[kk][nq * 4] = b4;
        }
        __syncthreads();
#pragma unroll
        for (int kk = 0; kk < GBK; ++kk) {
            float a[TM], b[TN];
#pragma unroll
            for (int iq = 0; iq < TM / 4; ++iq)
                *(float4*)&a[iq * 4] = *(const float4*)&As[kk][ty * TM + iq * 4];
#pragma unroll
            for (int jq = 0; jq < TN / 4; ++jq)
                *(float4*)&b[jq * 4] = *(const float4*)&Bs[kk][tx * TN + jq * 4];
#pragma unroll
            for (int i = 0; i < TM; ++i)
#pragma unroll
                for (int j = 0; j < TN; ++j) acc[i][j] += a[i] * b[j];
        }
        __syncthreads();
    }
#pragma unroll
    for (int i = 0; i < TM; ++i) {
        float* crow = C + (size_t)(m0 + ty * TM + i) * N + n0 + tx * TN;
#pragma unroll
        for (int jq = 0; jq < TN / 4; ++jq) {
            float4 cv = make_float4(acc[i][jq * 4 + 0], acc[i][jq * 4 + 1],
                                    acc[i][jq * 4 + 2], acc[i][jq * 4 + 3]);
            if (ACCUM) {
                float4 old = *(float4*)(crow + jq * 4);
                cv.x += old.x; cv.y += old.y; cv.z += old.z; cv.w += old.w;
            }
            *(float4*)(crow + jq * 4) = cv;
        }
    }
}

// ---------------- causal depthwise conv (K=4) + SiLU ----------------
__global__ __launch_bounds__(256) void k_conv(const float* __restrict__ xz,
                                              const float* __restrict__ cw,
                                              const float* __restrict__ cb,
                                              float* __restrict__ xc) {
    int idx = blockIdx.x * 256 + threadIdx.x;  // < BT_*E_
    int e = idx % E_;
    int bt = idx / E_;
    int t = bt & (L_ - 1);
    const float* base = xz + (size_t)bt * (2 * E_) + e;
    float w0 = cw[e * 4 + 0], w1 = cw[e * 4 + 1], w2 = cw[e * 4 + 2], w3 = cw[e * 4 + 3];
    float acc = cb[e] + base[0] * w3;
    if (t >= 1) acc += base[-(2 * E_)] * w2;
    if (t >= 2) acc += base[-(4 * E_)] * w1;
    if (t >= 3) acc += base[-(6 * E_)] * w0;
    xc[idx] = siluf_(acc);
}

// ---------------- x_proj: proj[bt,0:80] = xc[bt,:] @ w[1536,80] ----------------
__global__ __launch_bounds__(128) void k_xproj(const float* __restrict__ xc,
                                               const float* __restrict__ w,
                                               float* __restrict__ proj) {
    __shared__ float xr[4][E_];
    int bt0 = blockIdx.x * 4;
    for (int c = threadIdx.x; c < 4 * E_; c += 128)
        ((float*)xr)[c] = xc[(size_t)bt0 * E_ + c];
    __syncthreads();
    int j = threadIdx.x;
    if (j < (R_ + 2 * N_)) {
        float a0 = 0, a1 = 0, a2 = 0, a3 = 0;
#pragma unroll 4
        for (int k = 0; k < E_; ++k) {
            float wv = w[k * (R_ + 2 * N_) + j];
            a0 += xr[0][k] * wv;
            a1 += xr[1][k] * wv;
            a2 += xr[2][k] * wv;
            a3 += xr[3][k] * wv;
        }
        proj[(size_t)(bt0 + 0) * 80 + j] = a0;
        proj[(size_t)(bt0 + 1) * 80 + j] = a1;
        proj[(size_t)(bt0 + 2) * 80 + j] = a2;
        proj[(size_t)(bt0 + 3) * 80 + j] = a3;
    }
}

// ---------------- dt: softplus(proj[:,0:48] @ dw + db) ----------------
__global__ __launch_bounds__(256) void k_dt(const float* __restrict__ proj,
                                            const float* __restrict__ dw,
                                            const float* __restrict__ db,
                                            float* __restrict__ dt) {
    __shared__ float pr[4][R_];
    int bt0 = blockIdx.x * 4;
    if (threadIdx.x < 4 * R_)
        pr[threadIdx.x / R_][threadIdx.x % R_] =
            proj[(size_t)(bt0 + threadIdx.x / R_) * 80 + (threadIdx.x % R_)];
    __syncthreads();
#pragma unroll
    for (int rr = 0; rr < 6; ++rr) {
        int e = threadIdx.x + rr * 256;
        float bv = db[e];
        float a0 = bv, a1 = bv, a2 = bv, a3 = bv;
#pragma unroll 4
        for (int k = 0; k < R_; ++k) {
            float wv = dw[k * E_ + e];
            a0 += pr[0][k] * wv;
            a1 += pr[1][k] * wv;
            a2 += pr[2][k] * wv;
            a3 += pr[3][k] * wv;
        }
        dt[(size_t)(bt0 + 0) * E_ + e] = softplusf_(a0);
        dt[(size_t)(bt0 + 1) * E_ + e] = softplusf_(a1);
        dt[(size_t)(bt0 + 2) * E_ + e] = softplusf_(a2);
        dt[(size_t)(bt0 + 3) * E_ + e] = softplusf_(a3);
    }
}

// ---------------- selective scan: 16 lanes per (b,e); fused y*silu(z) ----------------
__global__ __launch_bounds__(256) void k_scan(const float* __restrict__ xc,
                                              const float* __restrict__ dt,
                                              const float* __restrict__ proj,
                                              const float* __restrict__ xz,
                                              const float* __restrict__ A_log,
                                              const float* __restrict__ Dp,
                                              float* __restrict__ yz) {
    int g = blockIdx.x * 16 + (threadIdx.x >> 4);  // [0, B_*E_)
    int n = threadIdx.x & 15;
    int b = g / E_;
    int e = g - b * E_;
    float A = -expf(A_log[e * N_ + n]);
    float dpe = Dp[e];

    size_t rbase = (size_t)b * L_ * E_ + e;
    size_t pbase = (size_t)b * L_ * 80;
    size_t zbase = (size_t)b * L_ * (2 * E_) + E_ + e;

    float hst = 0.0f;
    float dtv = dt[rbase], xv = xc[rbase];
    float Bv = proj[pbase + R_ + n], Cv = proj[pbase + R_ + N_ + n];
    float zv = xz[zbase];

    for (int t = 0; t < L_; ++t) {
        float dtn = 0, xn = 0, Bn = 0, Cn = 0, zn = 0;
        if (t < L_ - 1) {
            size_t r2 = rbase + (size_t)(t + 1) * E_;
            dtn = dt[r2];
            xn = xc[r2];
            size_t p2 = pbase + (size_t)(t + 1) * 80;
            Bn = proj[p2 + R_ + n];
            Cn = proj[p2 + R_ + N_ + n];
            zn = xz[zbase + (size_t)(t + 1) * (2 * E_)];
        }
        float dA = expf(dtv * A);
        hst = dA * hst + (dtv * xv) * Bv;
        float p = hst * Cv;
        p += __shfl_xor(p, 1);
        p += __shfl_xor(p, 2);
        p += __shfl_xor(p, 4);
        p += __shfl_xor(p, 8);
        float y = p + xv * dpe;
        float outv = y * siluf_(zv);
        if (n == 0) yz[rbase + (size_t)t * E_] = outv;
        dtv = dtn; xv = xn; Bv = Bn; Cv = Cn; zv = zn;
    }
}

// ---------------- head: hrel = relu(cls @ top_w + top_b), parallel over H ----------------
// grid = H_/64 blocks; block 256: jl = tid&63 (column), kq = tid>>6 (k quarter)
__global__ __launch_bounds__(256) void k_top(const float* __restrict__ cls,
                                             const float* __restrict__ w,
                                             const float* __restrict__ bias,
                                             float* __restrict__ hrel) {
    __shared__ float xs[B_][DM];          // 12 KB
    __shared__ float red[4][64][B_];      // 4 KB
    int tid = threadIdx.x;
    for (int c = tid; c < B_ * DM; c += 256) ((float*)xs)[c] = cls[c];
    __syncthreads();
    int jl = tid & 63;
    int kq = tid >> 6;
    int j = blockIdx.x * 64 + jl;
    float acc[B_] = {};
    for (int k = kq * (DM / 4); k < (kq + 1) * (DM / 4); ++k) {
        float wv = w[(size_t)k * H_ + j];
#pragma unroll
        for (int b = 0; b < B_; ++b) acc[b] += xs[b][k] * wv;
    }
#pragma unroll
    for (int b = 0; b < B_; ++b) red[kq][jl][b] = acc[b];
    __syncthreads();
    if (kq == 0) {
        float bv = bias[j];
#pragma unroll
        for (int b = 0; b < B_; ++b) {
            float s = red[0][jl][b] + red[1][jl][b] + red[2][jl][b] + red[3][jl][b] + bv;
            hrel[(size_t)b * H_ + j] = fmaxf(s, 0.0f);
        }
    }
}

// ---------------- head: out[b,:] = hrel[b,:] @ bot_w + bot_b, k-split 8 ----------------
// grid = B_; block 256: jl = tid&31 (col, <28 valid), kq = tid>>5 (k eighth)
__global__ __launch_bounds__(256) void k_bot(const float* __restrict__ hrel,
                                             const float* __restrict__ w,
                                             const float* __restrict__ bias,
                                             float* __restrict__ out) {
    __shared__ float red[8][T_];
    int b = blockIdx.x;
    int jl = threadIdx.x & 31;
    int kq = threadIdx.x >> 5;
    if (jl < T_) {
        float acc = 0.0f;
        for (int k = kq * (H_ / 8); k < (kq + 1) * (H_ / 8); ++k)
            acc += hrel[(size_t)b * H_ + k] * w[(size_t)k * T_ + jl];
        red[kq][jl] = acc;
    }
    __syncthreads();
    if (kq == 0 && jl < T_) {
        float s = bias[jl];
#pragma unroll
        for (int q = 0; q < 8; ++q) s += red[q][jl];
        out[(size_t)b * T_ + jl] = s;
    }
}

extern "C" void kernel_launch(void* const* d_in, const int* in_sizes, int n_in,
                              void* d_out, int out_size, void* d_ws, size_t ws_size,
                              hipStream_t stream) {
    const int*   ids       = (const int*)d_in[0];
    const float* embed     = (const float*)d_in[1];
    const float* in_proj_w = (const float*)d_in[2];
    const float* conv_w    = (const float*)d_in[3];
    const float* conv_b    = (const float*)d_in[4];
    const float* x_proj_w  = (const float*)d_in[5];
    const float* dt_w      = (const float*)d_in[6];
    const float* dt_b      = (const float*)d_in[7];
    const float* A_log     = (const float*)d_in[8];
    const float* D_p       = (const float*)d_in[9];
    const float* out_w     = (const float*)d_in[10];
    const float* norm_w    = (const float*)d_in[11];
    const float* norm_f_w  = (const float*)d_in[12];
    const float* top_w     = (const float*)d_in[13];
    const float* top_b     = (const float*)d_in[14];
    const float* bot_w     = (const float*)d_in[15];
    const float* bot_b     = (const float*)d_in[16];
    float* out = (float*)d_out;

    // workspace layout (floats)
    float* ws = (float*)d_ws;
    float* h    = ws;                        // 2048*768
    float* xi   = h + (size_t)BT_ * DM;      // 2048*768
    float* xz   = xi + (size_t)BT_ * DM;     // 2048*3072
    float* xc   = xz + (size_t)BT_ * 2 * E_; // 2048*1536
    float* proj = xc + (size_t)BT_ * E_;     // 2048*80
    float* dtb  = proj + (size_t)BT_ * 80;   // 2048*1536
    float* yz   = dtb + (size_t)BT_ * E_;    // 2048*1536
    float* cls  = yz + (size_t)BT_ * E_;     // 4*768
    float* hrel = cls + (size_t)B_ * DM;     // 4*1536

    k_embed<<<BT_, 256, 0, stream>>>(ids, embed, h);

    for (int i = 0; i < NL_; ++i) {
        const float* ipw = in_proj_w + (size_t)i * DM * 2 * E_;
        const float* cwi = conv_w + (size_t)i * E_ * K_;
        const float* cbi = conv_b + (size_t)i * E_;
        const float* xpw = x_proj_w + (size_t)i * E_ * (R_ + 2 * N_);
        const float* dwi = dt_w + (size_t)i * R_ * E_;
        const float* dbi = dt_b + (size_t)i * E_;
        const float* ali = A_log + (size_t)i * E_ * N_;
        const float* dpi = D_p + (size_t)i * E_;
        const float* owi = out_w + (size_t)i * E_ * DM;
        const float* nwi = norm_w + (size_t)i * DM;

        k_rmsnorm<<<BT_, 256, 0, stream>>>(h, DM, nwi, xi, DM);
        // in_proj: 2048 x 3072, K=768 — 128x128 tile, 8x8 microtile
        k_gemm<128, 128, 8, 8, false><<<dim3(2 * E_ / 128, BT_ / 128), 256, 0, stream>>>(
            xi, ipw, xz, BT_, 2 * E_, DM);
        k_conv<<<BT_ * E_ / 256, 256, 0, stream>>>(xz, cwi, cbi, xc);
        k_xproj<<<BT_ / 4, 128, 0, stream>>>(xc, xpw, proj);
        k_dt<<<BT_ / 4, 256, 0, stream>>>(proj, dwi, dbi, dtb);
        k_scan<<<B_ * E_ / 16, 256, 0, stream>>>(xc, dtb, proj, xz, ali, dpi, yz);
        // out_proj: 2048 x 768, K=1536 — 128x64 tile, 8x4 microtile (192 blocks)
        k_gemm<128, 64, 8, 4, true><<<dim3(DM / 64, BT_ / 128), 256, 0, stream>>>(
            yz, owi, h, BT_, DM, E_);
    }

    k_rmsnorm<<<B_, 256, 0, stream>>>(h + (size_t)(L_ - 1) * DM, (long)L_ * DM,
                                      norm_f_w, cls, DM);
    k_top<<<H_ / 64, 256, 0, stream>>>(cls, top_w, top_b, hrel);
    k_bot<<<B_, 256, 0, stream>>>(hrel, bot_w, bot_b, out);
}

// Round 3
// 2770.432 us; speedup vs baseline: 1.2984x; 1.1527x over previous
//
#include <hip/hip_runtime.h>
#include <hip/hip_bf16.h>
#include <math.h>

// Problem constants
#define B_ 4
#define L_ 512
#define DM 768
#define E_ 1536
#define N_ 16
#define R_ 48
#define K_ 4
#define NL_ 4
#define H_ 1536
#define T_ 28
#define BT_ (B_ * L_)   // 2048 tokens

__device__ __forceinline__ float sigmoidf_(float v) { return 1.0f / (1.0f + expf(-v)); }
__device__ __forceinline__ float siluf_(float v) { return v * sigmoidf_(v); }
__device__ __forceinline__ float softplusf_(float v) {
    return fmaxf(v, 0.0f) + log1pf(expf(-fabsf(v)));
}

// ---------------- embed gather ----------------
__global__ __launch_bounds__(256) void k_embed(const int* __restrict__ ids,
                                               const float* __restrict__ embed,
                                               float* __restrict__ h) {
    int bt = blockIdx.x;
    int tok = ids[bt];
    const float* src = embed + (size_t)tok * DM;
    float* dst = h + (size_t)bt * DM;
    for (int c = threadIdx.x; c < DM; c += 256) dst[c] = src[c];
}

// ---------------- RMSNorm (row per block, D=768) ----------------
__global__ __launch_bounds__(256) void k_rmsnorm(const float* __restrict__ base, long rstride,
                                                 const float* __restrict__ w,
                                                 float* __restrict__ out, long ostride) {
    int tid = threadIdx.x;
    const float* row = base + (size_t)blockIdx.x * rstride;
    float v0 = row[tid], v1 = row[tid + 256], v2 = row[tid + 512];
    float s = v0 * v0 + v1 * v1 + v2 * v2;
#pragma unroll
    for (int m = 1; m < 64; m <<= 1) s += __shfl_xor(s, m);
    __shared__ float red[4];
    if ((tid & 63) == 0) red[tid >> 6] = s;
    __syncthreads();
    s = red[0] + red[1] + red[2] + red[3];
    float rs = rsqrtf(s * (1.0f / (float)DM) + 1e-5f);
    float* orow = out + (size_t)blockIdx.x * ostride;
    orow[tid]       = v0 * rs * w[tid];
    orow[tid + 256] = v1 * rs * w[tid + 256];
    orow[tid + 512] = v2 * rs * w[tid + 512];
}

// ---------------- f32 GEMM: C[M,N] = A[M,K] @ B[K,N] (+= if ACCUM) ----------------
#define GBK 16
template <int BM, int BN, int TM, int TN, bool ACCUM>
__global__ __launch_bounds__(256) void k_gemm(const float* __restrict__ A,
                                              const float* __restrict__ Bm,
                                              float* __restrict__ C,
                                              int M, int N, int K) {
    __shared__ float As[GBK][BM + 4];
    __shared__ float Bs[GBK][BN + 4];
    int tid = threadIdx.x;
    int tx = tid & 15;   // n
    int ty = tid >> 4;   // m
    int m0 = blockIdx.y * BM;
    int n0 = blockIdx.x * BN;

    float acc[TM][TN] = {};

    constexpr int QA = BM / 64;
    constexpr int QB = BN / 64;

    for (int k0 = 0; k0 < K; k0 += GBK) {
#pragma unroll
        for (int i = 0; i < QA; ++i) {
            int idx = tid + i * 256;
            int m = idx >> 2;
            int kq = idx & 3;
            float4 a4 = *(const float4*)(A + (size_t)(m0 + m) * K + k0 + kq * 4);
            As[kq * 4 + 0][m] = a4.x;
            As[kq * 4 + 1][m] = a4.y;
            As[kq * 4 + 2][m] = a4.z;
            As[kq * 4 + 3][m] = a4.w;
        }
#pragma unroll
        for (int i = 0; i < QB; ++i) {
            int idx = tid + i * 256;
            int kk = idx / (BN / 4);
            int nq = idx % (BN / 4);
            float4 b4 = *(const float4*)(Bm + (size_t)(k0 + kk) * N + n0 + nq * 4);
            *(float4*)&Bs[kk][nq * 4] = b4;
        }
        __syncthreads();
#pragma unroll
        for (int kk = 0; kk < GBK; ++kk) {
            float a[TM], b[TN];
#pragma unroll
            for (int iq = 0; iq < TM / 4; ++iq)
                *(float4*)&a[iq * 4] = *(const float4*)&As[kk][ty * TM + iq * 4];
#pragma unroll
            for (int jq = 0; jq < TN / 4; ++jq)
                *(float4*)&b[jq * 4] = *(const float4*)&Bs[kk][tx * TN + jq * 4];
#pragma unroll
            for (int i = 0; i < TM; ++i)
#pragma unroll
                for (int j = 0; j < TN; ++j) acc[i][j] += a[i] * b[j];
        }
        __syncthreads();
    }
#pragma unroll
    for (int i = 0; i < TM; ++i) {
        float* crow = C + (size_t)(m0 + ty * TM + i) * N + n0 + tx * TN;
#pragma unroll
        for (int jq = 0; jq < TN / 4; ++jq) {
            float4 cv = make_float4(acc[i][jq * 4 + 0], acc[i][jq * 4 + 1],
                                    acc[i][jq * 4 + 2], acc[i][jq * 4 + 3]);
            if (ACCUM) {
                float4 old = *(float4*)(crow + jq * 4);
                cv.x += old.x; cv.y += old.y; cv.z += old.z; cv.w += old.w;
            }
            *(float4*)(crow + jq * 4) = cv;
        }
    }
}

// ---------------- causal depthwise conv (K=4) + SiLU ----------------
__global__ __launch_bounds__(256) void k_conv(const float* __restrict__ xz,
                                              const float* __restrict__ cw,
                                              const float* __restrict__ cb,
                                              float* __restrict__ xc) {
    int idx = blockIdx.x * 256 + threadIdx.x;
    int e = idx % E_;
    int bt = idx / E_;
    int t = bt & (L_ - 1);
    const float* base = xz + (size_t)bt * (2 * E_) + e;
    float w0 = cw[e * 4 + 0], w1 = cw[e * 4 + 1], w2 = cw[e * 4 + 2], w3 = cw[e * 4 + 3];
    float acc = cb[e] + base[0] * w3;
    if (t >= 1) acc += base[-(2 * E_)] * w2;
    if (t >= 2) acc += base[-(4 * E_)] * w1;
    if (t >= 3) acc += base[-(6 * E_)] * w0;
    xc[idx] = siluf_(acc);
}

// ---------------- x_proj: proj[bt,0:80] = xc[bt,:] @ w[1536,80] ----------------
__global__ __launch_bounds__(128) void k_xproj(const float* __restrict__ xc,
                                               const float* __restrict__ w,
                                               float* __restrict__ proj) {
    __shared__ float xr[4][E_];
    int bt0 = blockIdx.x * 4;
    for (int c = threadIdx.x; c < 4 * E_; c += 128)
        ((float*)xr)[c] = xc[(size_t)bt0 * E_ + c];
    __syncthreads();
    int j = threadIdx.x;
    if (j < (R_ + 2 * N_)) {
        float a0 = 0, a1 = 0, a2 = 0, a3 = 0;
#pragma unroll 4
        for (int k = 0; k < E_; ++k) {
            float wv = w[k * (R_ + 2 * N_) + j];
            a0 += xr[0][k] * wv;
            a1 += xr[1][k] * wv;
            a2 += xr[2][k] * wv;
            a3 += xr[3][k] * wv;
        }
        proj[(size_t)(bt0 + 0) * 80 + j] = a0;
        proj[(size_t)(bt0 + 1) * 80 + j] = a1;
        proj[(size_t)(bt0 + 2) * 80 + j] = a2;
        proj[(size_t)(bt0 + 3) * 80 + j] = a3;
    }
}

// ---------------- k_prep: dt GEMM(K=48)+softplus, plus transposed scan inputs ----------------
// Tile 64t x 64e per block; writes dtT/dxT/xdT/zsT in [b][e][t] (time-contiguous) layout.
__global__ __launch_bounds__(256) void k_prep(const float* __restrict__ proj,
                                              const float* __restrict__ dw,
                                              const float* __restrict__ db,
                                              const float* __restrict__ xc,
                                              const float* __restrict__ xz,
                                              const float* __restrict__ dp,
                                              float* __restrict__ dtT,
                                              float* __restrict__ dxT,
                                              float* __restrict__ xdT,
                                              float* __restrict__ zsT) {
    __shared__ float projS[64][48];
    __shared__ float dwS[48][64];
    __shared__ float tileT[64][65];
    int b = blockIdx.z;
    int t0 = blockIdx.x * 64;
    int e0 = blockIdx.y * 64;
    int tid = threadIdx.x;

    for (int idx = tid; idx < 64 * 48; idx += 256) {
        int tl = idx / 48, k = idx % 48;
        projS[tl][k] = proj[(size_t)(b * L_ + t0 + tl) * 80 + k];
    }
    for (int idx = tid; idx < 48 * 64; idx += 256) {
        int k = idx >> 6, ee = idx & 63;
        dwS[k][ee] = dw[(size_t)k * E_ + e0 + ee];
    }
    __syncthreads();

    int el = tid & 63;       // e offset (lane within wave)
    int tg = tid >> 6;       // t group: t = t0 + tg*16 + s
    float acc[16];
    float bvE = db[e0 + el];
#pragma unroll
    for (int s = 0; s < 16; ++s) acc[s] = bvE;
    for (int k = 0; k < 48; ++k) {
        float wv = dwS[k][el];
#pragma unroll
        for (int s = 0; s < 16; ++s) acc[s] += projS[tg * 16 + s][k] * wv;
    }
    float dtv[16];
#pragma unroll
    for (int s = 0; s < 16; ++s) dtv[s] = softplusf_(acc[s]);
    float xv[16];
#pragma unroll
    for (int s = 0; s < 16; ++s)
        xv[s] = xc[(size_t)(b * L_ + t0 + tg * 16 + s) * E_ + e0 + el];
    float dpv = dp[e0 + el];

#define XPOSE_OUT(dst, EXPR)                                                      \
    do {                                                                          \
        __syncthreads();                                                          \
        for (int s = 0; s < 16; ++s) tileT[el][tg * 16 + s] = (EXPR);             \
        __syncthreads();                                                          \
        for (int idx = tid; idx < 4096; idx += 256) {                             \
            int e2 = idx >> 6, t2 = idx & 63;                                     \
            dst[((size_t)b * E_ + e0 + e2) * L_ + t0 + t2] = tileT[e2][t2];       \
        }                                                                         \
    } while (0)

    XPOSE_OUT(dtT, dtv[s]);
    XPOSE_OUT(dxT, dtv[s] * xv[s]);
    XPOSE_OUT(xdT, xv[s] * dpv);
    float zv[16];
#pragma unroll
    for (int s = 0; s < 16; ++s)
        zv[s] = xz[(size_t)(b * L_ + t0 + tg * 16 + s) * (2 * E_) + E_ + e0 + el];
    XPOSE_OUT(zsT, siluf_(zv[s]));
#undef XPOSE_OUT
}

// ---------------- chunked parallel selective scan ----------------
// block per (b,e): 256 threads = 16 chunks (c) x 16 state dims (n); 32 t per chunk.
__global__ __launch_bounds__(256) void k_scan2(const float* __restrict__ dtT,
                                               const float* __restrict__ dxT,
                                               const float* __restrict__ xdT,
                                               const float* __restrict__ zsT,
                                               const float* __restrict__ proj,
                                               const float* __restrict__ A_log,
                                               float* __restrict__ yz) {
    __shared__ float s_dt[L_], s_xd[L_], s_zs[L_];
    __shared__ float sAP[16][17], sAS[16][17], sH[16][17];
    int tid = threadIdx.x;
    int b = blockIdx.x / E_;
    int e = blockIdx.x - b * E_;
    size_t base = ((size_t)b * E_ + e) * L_;

    for (int idx = tid; idx < L_; idx += 256) {
        s_dt[idx] = dtT[base + idx];
        s_xd[idx] = xdT[base + idx];
        s_zs[idx] = zsT[base + idx];
    }
    int c = tid >> 4;
    int n = tid & 15;
    float A = -expf(A_log[e * N_ + n]);
    __syncthreads();

    int t0 = c * 32;
    const float* pb = proj + (size_t)(b * L_ + t0) * 80 + R_ + n;
    const float* pdx = dxT + base + t0;

    // phase 1: per-chunk (P, S) with dA,u cached in registers
    float dAr[32], ur[32];
    float P = 1.0f, S = 0.0f;
#pragma unroll
    for (int s = 0; s < 32; ++s) {
        float dtv = s_dt[t0 + s];
        float dA = expf(dtv * A);
        float u = pdx[s] * pb[s * 80];
        dAr[s] = dA;
        ur[s] = u;
        P *= dA;
        S = dA * S + u;
    }
    sAP[c][n] = P;
    sAS[c][n] = S;
    __syncthreads();
    // chunk-prefix scan (16 chunks, serial by 16 threads)
    if (tid < 16) {
        float H = 0.0f;
        for (int c2 = 0; c2 < 16; ++c2) {
            sH[c2][tid] = H;
            H = sAP[c2][tid] * H + sAS[c2][tid];
        }
    }
    __syncthreads();

    // phase 2: replay with correct h_init; y reduce over n; fused output
    float h = sH[c][n];
    const float* pc = proj + (size_t)(b * L_ + t0) * 80 + R_ + N_ + n;
#pragma unroll
    for (int s = 0; s < 32; ++s) {
        h = dAr[s] * h + ur[s];
        float p = h * pc[s * 80];
        p += __shfl_xor(p, 1);
        p += __shfl_xor(p, 2);
        p += __shfl_xor(p, 4);
        p += __shfl_xor(p, 8);
        if (n == 0)
            yz[(size_t)(b * L_ + t0 + s) * E_ + e] = (p + s_xd[t0 + s]) * s_zs[t0 + s];
    }
}

// ---------------- head: hrel = relu(cls @ top_w + top_b) ----------------
__global__ __launch_bounds__(256) void k_top(const float* __restrict__ cls,
                                             const float* __restrict__ w,
                                             const float* __restrict__ bias,
                                             float* __restrict__ hrel) {
    __shared__ float xs[B_][DM];
    __shared__ float red[4][64][B_];
    int tid = threadIdx.x;
    for (int c = tid; c < B_ * DM; c += 256) ((float*)xs)[c] = cls[c];
    __syncthreads();
    int jl = tid & 63;
    int kq = tid >> 6;
    int j = blockIdx.x * 64 + jl;
    float acc[B_] = {};
    for (int k = kq * (DM / 4); k < (kq + 1) * (DM / 4); ++k) {
        float wv = w[(size_t)k * H_ + j];
#pragma unroll
        for (int b = 0; b < B_; ++b) acc[b] += xs[b][k] * wv;
    }
#pragma unroll
    for (int b = 0; b < B_; ++b) red[kq][jl][b] = acc[b];
    __syncthreads();
    if (kq == 0) {
        float bv = bias[j];
#pragma unroll
        for (int b = 0; b < B_; ++b) {
            float s = red[0][jl][b] + red[1][jl][b] + red[2][jl][b] + red[3][jl][b] + bv;
            hrel[(size_t)b * H_ + j] = fmaxf(s, 0.0f);
        }
    }
}

// ---------------- head: out = hrel @ bot_w + bot_b ----------------
__global__ __launch_bounds__(256) void k_bot(const float* __restrict__ hrel,
                                             const float* __restrict__ w,
                                             const float* __restrict__ bias,
                                             float* __restrict__ out) {
    __shared__ float red[8][T_];
    int b = blockIdx.x;
    int jl = threadIdx.x & 31;
    int kq = threadIdx.x >> 5;
    if (jl < T_) {
        float acc = 0.0f;
        for (int k = kq * (H_ / 8); k < (kq + 1) * (H_ / 8); ++k)
            acc += hrel[(size_t)b * H_ + k] * w[(size_t)k * T_ + jl];
        red[kq][jl] = acc;
    }
    __syncthreads();
    if (kq == 0 && jl < T_) {
        float s = bias[jl];
#pragma unroll
        for (int q = 0; q < 8; ++q) s += red[q][jl];
        out[(size_t)b * T_ + jl] = s;
    }
}

extern "C" void kernel_launch(void* const* d_in, const int* in_sizes, int n_in,
                              void* d_out, int out_size, void* d_ws, size_t ws_size,
                              hipStream_t stream) {
    const int*   ids       = (const int*)d_in[0];
    const float* embed     = (const float*)d_in[1];
    const float* in_proj_w = (const float*)d_in[2];
    const float* conv_w    = (const float*)d_in[3];
    const float* conv_b    = (const float*)d_in[4];
    const float* x_proj_w  = (const float*)d_in[5];
    const float* dt_w      = (const float*)d_in[6];
    const float* dt_b      = (const float*)d_in[7];
    const float* A_log     = (const float*)d_in[8];
    const float* D_p       = (const float*)d_in[9];
    const float* out_w     = (const float*)d_in[10];
    const float* norm_w    = (const float*)d_in[11];
    const float* norm_f_w  = (const float*)d_in[12];
    const float* top_w     = (const float*)d_in[13];
    const float* top_b     = (const float*)d_in[14];
    const float* bot_w     = (const float*)d_in[15];
    const float* bot_b     = (const float*)d_in[16];
    float* out = (float*)d_out;

    // workspace layout (floats)
    float* ws = (float*)d_ws;
    float* h    = ws;                         // 2048*768
    float* xi   = h + (size_t)BT_ * DM;       // 2048*768
    float* xz   = xi + (size_t)BT_ * DM;      // 2048*3072
    float* xc   = xz + (size_t)BT_ * 2 * E_;  // 2048*1536
    float* proj = xc + (size_t)BT_ * E_;      // 2048*80
    float* yz   = proj + (size_t)BT_ * 80;    // 2048*1536
    float* dtT  = yz + (size_t)BT_ * E_;      // 2048*1536 ([b][e][t])
    float* dxT  = dtT + (size_t)BT_ * E_;     // 2048*1536
    float* xdT  = dxT + (size_t)BT_ * E_;     // 2048*1536
    float* zsT  = xdT + (size_t)BT_ * E_;     // 2048*1536
    float* cls  = zsT + (size_t)BT_ * E_;     // 4*768
    float* hrel = cls + (size_t)B_ * DM;      // 4*1536

    k_embed<<<BT_, 256, 0, stream>>>(ids, embed, h);

    for (int i = 0; i < NL_; ++i) {
        const float* ipw = in_proj_w + (size_t)i * DM * 2 * E_;
        const float* cwi = conv_w + (size_t)i * E_ * K_;
        const float* cbi = conv_b + (size_t)i * E_;
        const float* xpw = x_proj_w + (size_t)i * E_ * (R_ + 2 * N_);
        const float* dwi = dt_w + (size_t)i * R_ * E_;
        const float* dbi = dt_b + (size_t)i * E_;
        const float* ali = A_log + (size_t)i * E_ * N_;
        const float* dpi = D_p + (size_t)i * E_;
        const float* owi = out_w + (size_t)i * E_ * DM;
        const float* nwi = norm_w + (size_t)i * DM;

        k_rmsnorm<<<BT_, 256, 0, stream>>>(h, DM, nwi, xi, DM);
        k_gemm<128, 128, 8, 8, false><<<dim3(2 * E_ / 128, BT_ / 128), 256, 0, stream>>>(
            xi, ipw, xz, BT_, 2 * E_, DM);
        k_conv<<<BT_ * E_ / 256, 256, 0, stream>>>(xz, cwi, cbi, xc);
        k_xproj<<<BT_ / 4, 128, 0, stream>>>(xc, xpw, proj);
        k_prep<<<dim3(L_ / 64, E_ / 64, B_), 256, 0, stream>>>(
            proj, dwi, dbi, xc, xz, dpi, dtT, dxT, xdT, zsT);
        k_scan2<<<B_ * E_, 256, 0, stream>>>(dtT, dxT, xdT, zsT, proj, ali, yz);
        k_gemm<128, 64, 8, 4, true><<<dim3(DM / 64, BT_ / 128), 256, 0, stream>>>(
            yz, owi, h, BT_, DM, E_);
    }

    k_rmsnorm<<<B_, 256, 0, stream>>>(h + (size_t)(L_ - 1) * DM, (long)L_ * DM,
                                      norm_f_w, cls, DM);
    k_top<<<H_ / 64, 256, 0, stream>>>(cls, top_w, top_b, hrel);
    k_bot<<<B_, 256, 0, stream>>>(hrel, bot_w, bot_b, out);
}

// Round 5
// 2090.249 us; speedup vs baseline: 1.7209x; 1.3254x over previous
//
#include <hip/hip_runtime.h>
#include <hip/hip_bf16.h>
#include <math.h>

// Problem constants
#define B_ 4
#define L_ 512
#define DM 768
#define E_ 1536
#define N_ 16
#define R_ 48
#define K_ 4
#define NL_ 4
#define H_ 1536
#define T_ 28
#define BT_ (B_ * L_)   // 2048 tokens

typedef __bf16 bf16x8 __attribute__((ext_vector_type(8)));
typedef float  f32x4  __attribute__((ext_vector_type(4)));

__device__ __forceinline__ float sigmoidf_(float v) { return 1.0f / (1.0f + expf(-v)); }
__device__ __forceinline__ float siluf_(float v) { return v * sigmoidf_(v); }
__device__ __forceinline__ float softplusf_(float v) {
    return fmaxf(v, 0.0f) + log1pf(expf(-fabsf(v)));
}
// f32 -> bf16 (RNE) as bit pattern, and back
__device__ __forceinline__ unsigned short f2bf(float x) {
    unsigned u = __float_as_uint(x);
    u = u + 0x7fffu + ((u >> 16) & 1u);
    return (unsigned short)(u >> 16);
}
__device__ __forceinline__ float bf2f(unsigned short h) {
    return __uint_as_float(((unsigned)h) << 16);
}
// async global->LDS 16B per lane
__device__ __forceinline__ void gl_lds16(const void* g, void* l) {
    auto gp = reinterpret_cast<const __attribute__((address_space(1))) unsigned int*>(
        reinterpret_cast<uintptr_t>(g));
    auto lp = reinterpret_cast<__attribute__((address_space(3))) unsigned int*>(
        reinterpret_cast<uintptr_t>(l));
    __builtin_amdgcn_global_load_lds(gp, lp, 16, 0, 0);
}

// ---------------- embed gather ----------------
__global__ __launch_bounds__(256) void k_embed(const int* __restrict__ ids,
                                               const float* __restrict__ embed,
                                               float* __restrict__ h) {
    int bt = blockIdx.x;
    int tok = ids[bt];
    const float* src = embed + (size_t)tok * DM;
    float* dst = h + (size_t)bt * DM;
    for (int c = threadIdx.x; c < DM; c += 256) dst[c] = src[c];
}

// ---------------- RMSNorm; BF=true emits bf16 hi/lo split ----------------
template <bool BF>
__global__ __launch_bounds__(256) void k_rmsnorm(const float* __restrict__ base, long rstride,
                                                 const float* __restrict__ w,
                                                 float* __restrict__ outf,
                                                 unsigned short* __restrict__ oh,
                                                 unsigned short* __restrict__ ol) {
    int tid = threadIdx.x;
    const float* row = base + (size_t)blockIdx.x * rstride;
    float v0 = row[tid], v1 = row[tid + 256], v2 = row[tid + 512];
    float s = v0 * v0 + v1 * v1 + v2 * v2;
#pragma unroll
    for (int m = 1; m < 64; m <<= 1) s += __shfl_xor(s, m);
    __shared__ float red[4];
    if ((tid & 63) == 0) red[tid >> 6] = s;
    __syncthreads();
    s = red[0] + red[1] + red[2] + red[3];
    float rs = rsqrtf(s * (1.0f / (float)DM) + 1e-5f);
    float r0 = v0 * rs * w[tid];
    float r1 = v1 * rs * w[tid + 256];
    float r2 = v2 * rs * w[tid + 512];
    size_t o = (size_t)blockIdx.x * DM;
    if (BF) {
        unsigned short h0 = f2bf(r0), h1 = f2bf(r1), h2 = f2bf(r2);
        oh[o + tid] = h0;        ol[o + tid] = f2bf(r0 - bf2f(h0));
        oh[o + tid + 256] = h1;  ol[o + tid + 256] = f2bf(r1 - bf2f(h1));
        oh[o + tid + 512] = h2;  ol[o + tid + 512] = f2bf(r2 - bf2f(h2));
    } else {
        outf[o + tid] = r0;
        outf[o + tid + 256] = r1;
        outf[o + tid + 512] = r2;
    }
}

// ---------------- weight transpose + bf16 hi/lo split: w[K][N] -> wT_hi/lo[N][K] ----------------
__global__ __launch_bounds__(256) void k_wsplit(const float* __restrict__ w,
                                                unsigned short* __restrict__ th,
                                                unsigned short* __restrict__ tl,
                                                int K, int N) {
    __shared__ float t[32][33];
    int n0 = blockIdx.x * 32, k0 = blockIdx.y * 32;
    int c = threadIdx.x & 31, r0 = threadIdx.x >> 5;
#pragma unroll
    for (int it = 0; it < 4; ++it) {
        int r = r0 + it * 8;
        t[r][c] = w[(size_t)(k0 + r) * N + n0 + c];
    }
    __syncthreads();
#pragma unroll
    for (int it = 0; it < 4; ++it) {
        int r = r0 + it * 8;           // n offset
        float v = t[c][r];             // w[k0+c][n0+r]
        unsigned short h = f2bf(v);
        th[(size_t)(n0 + r) * K + k0 + c] = h;
        tl[(size_t)(n0 + r) * K + k0 + c] = f2bf(v - bf2f(h));
    }
}

// ---------------- MFMA GEMM (bf16x2 split): C[M,N] (+)= A[M,K] @ BT[N,K]^T ----------------
// 256 threads = 4 waves in 2x2; wave tile WM x WN of 16x16 frags; K-step 32.
// LDS layout per tensor-half: [oct(4)][row(BM|BN)][8] bf16, fragment-contiguous.
template <int BM, int BN, int WM, int WN, bool ACCUM>
__global__ __launch_bounds__(256) void k_mmf(const unsigned short* __restrict__ Ah,
                                             const unsigned short* __restrict__ Al,
                                             const unsigned short* __restrict__ Bh,
                                             const unsigned short* __restrict__ Bl,
                                             float* __restrict__ C,
                                             int M, int N, int K) {
    constexpr int MR = WM / 16, NR = WN / 16;
    __shared__ __align__(16) unsigned short sAh[4 * BM * 8], sAl[4 * BM * 8];
    __shared__ __align__(16) unsigned short sBh[4 * BN * 8], sBl[4 * BN * 8];
    int tid = threadIdx.x;
    int lane = tid & 63;
    int w = tid >> 6;
    int wr = w >> 1, wc = w & 1;
    int m0 = blockIdx.y * BM, n0 = blockIdx.x * BN;

    f32x4 acc[MR][NR] = {};

    constexpr int RA = (4 * BM) / 256;   // staging rounds for A
    constexpr int RB = (4 * BN) / 256;

    for (int k0 = 0; k0 < K; k0 += 32) {
#pragma unroll
        for (int r = 0; r < RA; ++r) {
            int cell = (r * 4 + w) * 64 + lane;
            int oct = cell / BM, row = cell % BM;
            size_t go = (size_t)(m0 + row) * K + k0 + oct * 8;
            gl_lds16(Ah + go, &sAh[(size_t)cell * 8]);
            gl_lds16(Al + go, &sAl[(size_t)cell * 8]);
        }
#pragma unroll
        for (int r = 0; r < RB; ++r) {
            int cell = (r * 4 + w) * 64 + lane;
            int oct = cell / BN, row = cell % BN;
            size_t go = (size_t)(n0 + row) * K + k0 + oct * 8;
            gl_lds16(Bh + go, &sBh[(size_t)cell * 8]);
            gl_lds16(Bl + go, &sBl[(size_t)cell * 8]);
        }
        asm volatile("s_waitcnt vmcnt(0)" ::: "memory");
        __syncthreads();

        int oct = lane >> 4;
        int rl = lane & 15;
        bf16x8 ah[MR], al[MR], bh[NR], bl[NR];
#pragma unroll
        for (int i = 0; i < MR; ++i) {
            int row = wr * WM + i * 16 + rl;
            ah[i] = *(const bf16x8*)&sAh[(oct * BM + row) * 8];
            al[i] = *(const bf16x8*)&sAl[(oct * BM + row) * 8];
        }
#pragma unroll
        for (int j = 0; j < NR; ++j) {
            int row = wc * WN + j * 16 + rl;
            bh[j] = *(const bf16x8*)&sBh[(oct * BN + row) * 8];
            bl[j] = *(const bf16x8*)&sBl[(oct * BN + row) * 8];
        }
#pragma unroll
        for (int i = 0; i < MR; ++i)
#pragma unroll
            for (int j = 0; j < NR; ++j) {
                acc[i][j] = __builtin_amdgcn_mfma_f32_16x16x32_bf16(ah[i], bh[j], acc[i][j], 0, 0, 0);
                acc[i][j] = __builtin_amdgcn_mfma_f32_16x16x32_bf16(ah[i], bl[j], acc[i][j], 0, 0, 0);
                acc[i][j] = __builtin_amdgcn_mfma_f32_16x16x32_bf16(al[i], bh[j], acc[i][j], 0, 0, 0);
            }
        __syncthreads();
    }
    int rl = lane & 15, rq = lane >> 4;
#pragma unroll
    for (int i = 0; i < MR; ++i)
#pragma unroll
        for (int j = 0; j < NR; ++j)
#pragma unroll
            for (int v = 0; v < 4; ++v) {
                int row = m0 + wr * WM + i * 16 + rq * 4 + v;
                int col = n0 + wc * WN + j * 16 + rl;
                float val = acc[i][j][v];
                if (ACCUM) val += C[(size_t)row * N + col];
                C[(size_t)row * N + col] = val;
            }
}

// ---------------- causal depthwise conv (K=4) + SiLU ----------------
__global__ __launch_bounds__(256) void k_conv(const float* __restrict__ xz,
                                              const float* __restrict__ cw,
                                              const float* __restrict__ cb,
                                              float* __restrict__ xc) {
    int idx = blockIdx.x * 256 + threadIdx.x;
    int e = idx % E_;
    int bt = idx / E_;
    int t = bt & (L_ - 1);
    const float* base = xz + (size_t)bt * (2 * E_) + e;
    float w0 = cw[e * 4 + 0], w1 = cw[e * 4 + 1], w2 = cw[e * 4 + 2], w3 = cw[e * 4 + 3];
    float acc = cb[e] + base[0] * w3;
    if (t >= 1) acc += base[-(2 * E_)] * w2;
    if (t >= 2) acc += base[-(4 * E_)] * w1;
    if (t >= 3) acc += base[-(6 * E_)] * w0;
    xc[idx] = siluf_(acc);
}

// ---------------- x_proj: proj[bt,0:80] = xc[bt,:] @ w[1536,80] ----------------
__global__ __launch_bounds__(128) void k_xproj(const float* __restrict__ xc,
                                               const float* __restrict__ w,
                                               float* __restrict__ proj) {
    __shared__ float xr[4][E_];
    int bt0 = blockIdx.x * 4;
    for (int c = threadIdx.x; c < 4 * E_; c += 128)
        ((float*)xr)[c] = xc[(size_t)bt0 * E_ + c];
    __syncthreads();
    int j = threadIdx.x;
    if (j < (R_ + 2 * N_)) {
        float a0 = 0, a1 = 0, a2 = 0, a3 = 0;
#pragma unroll 4
        for (int k = 0; k < E_; ++k) {
            float wv = w[k * (R_ + 2 * N_) + j];
            a0 += xr[0][k] * wv;
            a1 += xr[1][k] * wv;
            a2 += xr[2][k] * wv;
            a3 += xr[3][k] * wv;
        }
        proj[(size_t)(bt0 + 0) * 80 + j] = a0;
        proj[(size_t)(bt0 + 1) * 80 + j] = a1;
        proj[(size_t)(bt0 + 2) * 80 + j] = a2;
        proj[(size_t)(bt0 + 3) * 80 + j] = a3;
    }
}

// ---------------- k_prep: dt GEMM(K=48)+softplus + transposed scan inputs ----------------
__global__ __launch_bounds__(256) void k_prep(const float* __restrict__ proj,
                                              const float* __restrict__ dw,
                                              const float* __restrict__ db,
                                              const float* __restrict__ xc,
                                              const float* __restrict__ xz,
                                              const float* __restrict__ dp,
                                              float* __restrict__ dtT,
                                              float* __restrict__ dxT,
                                              float* __restrict__ xdT,
                                              float* __restrict__ zsT) {
    __shared__ float projS[64][48];
    __shared__ float dwS[48][64];
    __shared__ float tileT[64][65];
    int b = blockIdx.z;
    int t0 = blockIdx.x * 64;
    int e0 = blockIdx.y * 64;
    int tid = threadIdx.x;

    for (int idx = tid; idx < 64 * 48; idx += 256) {
        int tl = idx / 48, k = idx % 48;
        projS[tl][k] = proj[(size_t)(b * L_ + t0 + tl) * 80 + k];
    }
    for (int idx = tid; idx < 48 * 64; idx += 256) {
        int k = idx >> 6, ee = idx & 63;
        dwS[k][ee] = dw[(size_t)k * E_ + e0 + ee];
    }
    __syncthreads();

    int el = tid & 63;
    int tg = tid >> 6;
    float acc[16];
    float bvE = db[e0 + el];
#pragma unroll
    for (int s = 0; s < 16; ++s) acc[s] = bvE;
    for (int k = 0; k < 48; ++k) {
        float wv = dwS[k][el];
#pragma unroll
        for (int s = 0; s < 16; ++s) acc[s] += projS[tg * 16 + s][k] * wv;
    }
    float dtv[16];
#pragma unroll
    for (int s = 0; s < 16; ++s) dtv[s] = softplusf_(acc[s]);
    float xv[16];
#pragma unroll
    for (int s = 0; s < 16; ++s)
        xv[s] = xc[(size_t)(b * L_ + t0 + tg * 16 + s) * E_ + e0 + el];
    float dpv = dp[e0 + el];

#define XPOSE_OUT(dst, EXPR)                                                      \
    do {                                                                          \
        __syncthreads();                                                          \
        for (int s = 0; s < 16; ++s) tileT[el][tg * 16 + s] = (EXPR);             \
        __syncthreads();                                                          \
        for (int idx = tid; idx < 4096; idx += 256) {                             \
            int e2 = idx >> 6, t2 = idx & 63;                                     \
            dst[((size_t)b * E_ + e0 + e2) * L_ + t0 + t2] = tileT[e2][t2];       \
        }                                                                         \
    } while (0)

    XPOSE_OUT(dtT, dtv[s]);
    XPOSE_OUT(dxT, dtv[s] * xv[s]);
    XPOSE_OUT(xdT, xv[s] * dpv);
    float zv[16];
#pragma unroll
    for (int s = 0; s < 16; ++s)
        zv[s] = xz[(size_t)(b * L_ + t0 + tg * 16 + s) * (2 * E_) + E_ + e0 + el];
    XPOSE_OUT(zsT, siluf_(zv[s]));
#undef XPOSE_OUT
}

// ---------------- chunked parallel selective scan; emits yz as bf16 hi/lo ----------------
__global__ __launch_bounds__(256) void k_scan2(const float* __restrict__ dtT,
                                               const float* __restrict__ dxT,
                                               const float* __restrict__ xdT,
                                               const float* __restrict__ zsT,
                                               const float* __restrict__ proj,
                                               const float* __restrict__ A_log,
                                               unsigned short* __restrict__ yzh,
                                               unsigned short* __restrict__ yzl) {
    __shared__ float s_dt[L_], s_xd[L_], s_zs[L_];
    __shared__ float sAP[16][17], sAS[16][17], sH[16][17];
    int tid = threadIdx.x;
    int b = blockIdx.x / E_;
    int e = blockIdx.x - b * E_;
    size_t base = ((size_t)b * E_ + e) * L_;

    for (int idx = tid; idx < L_; idx += 256) {
        s_dt[idx] = dtT[base + idx];
        s_xd[idx] = xdT[base + idx];
        s_zs[idx] = zsT[base + idx];
    }
    int c = tid >> 4;
    int n = tid & 15;
    float A = -expf(A_log[e * N_ + n]);
    __syncthreads();

    int t0 = c * 32;
    const float* pb = proj + (size_t)(b * L_ + t0) * 80 + R_ + n;
    const float* pdx = dxT + base + t0;

    float dAr[32], ur[32];
    float P = 1.0f, S = 0.0f;
#pragma unroll
    for (int s = 0; s < 32; ++s) {
        float dtv = s_dt[t0 + s];
        float dA = expf(dtv * A);
        float u = pdx[s] * pb[s * 80];
        dAr[s] = dA;
        ur[s] = u;
        P *= dA;
        S = dA * S + u;
    }
    sAP[c][n] = P;
    sAS[c][n] = S;
    __syncthreads();
    if (tid < 16) {
        float H = 0.0f;
        for (int c2 = 0; c2 < 16; ++c2) {
            sH[c2][tid] = H;
            H = sAP[c2][tid] * H + sAS[c2][tid];
        }
    }
    __syncthreads();

    float h = sH[c][n];
    const float* pc = proj + (size_t)(b * L_ + t0) * 80 + R_ + N_ + n;
#pragma unroll
    for (int s = 0; s < 32; ++s) {
        h = dAr[s] * h + ur[s];
        float p = h * pc[s * 80];
        p += __shfl_xor(p, 1);
        p += __shfl_xor(p, 2);
        p += __shfl_xor(p, 4);
        p += __shfl_xor(p, 8);
        if (n == 0) {
            float v = (p + s_xd[t0 + s]) * s_zs[t0 + s];
            unsigned short hh = f2bf(v);
            size_t oidx = (size_t)(b * L_ + t0 + s) * E_ + e;
            yzh[oidx] = hh;
            yzl[oidx] = f2bf(v - bf2f(hh));
        }
    }
}

// ---------------- head: hrel = relu(cls @ top_w + top_b) ----------------
__global__ __launch_bounds__(256) void k_top(const float* __restrict__ cls,
                                             const float* __restrict__ w,
                                             const float* __restrict__ bias,
                                             float* __restrict__ hrel) {
    __shared__ float xs[B_][DM];
    __shared__ float red[4][64][B_];
    int tid = threadIdx.x;
    for (int c = tid; c < B_ * DM; c += 256) ((float*)xs)[c] = cls[c];
    __syncthreads();
    int jl = tid & 63;
    int kq = tid >> 6;
    int j = blockIdx.x * 64 + jl;
    float acc[B_] = {};
    for (int k = kq * (DM / 4); k < (kq + 1) * (DM / 4); ++k) {
        float wv = w[(size_t)k * H_ + j];
#pragma unroll
        for (int b = 0; b < B_; ++b) acc[b] += xs[b][k] * wv;
    }
#pragma unroll
    for (int b = 0; b < B_; ++b) red[kq][jl][b] = acc[b];
    __syncthreads();
    if (kq == 0) {
        float bv = bias[j];
#pragma unroll
        for (int b = 0; b < B_; ++b) {
            float s = red[0][jl][b] + red[1][jl][b] + red[2][jl][b] + red[3][jl][b] + bv;
            hrel[(size_t)b * H_ + j] = fmaxf(s, 0.0f);
        }
    }
}

// ---------------- head: out = hrel @ bot_w + bot_b ----------------
__global__ __launch_bounds__(256) void k_bot(const float* __restrict__ hrel,
                                             const float* __restrict__ w,
                                             const float* __restrict__ bias,
                                             float* __restrict__ out) {
    __shared__ float red[8][T_];
    int b = blockIdx.x;
    int jl = threadIdx.x & 31;
    int kq = threadIdx.x >> 5;
    if (jl < T_) {
        float acc = 0.0f;
        for (int k = kq * (H_ / 8); k < (kq + 1) * (H_ / 8); ++k)
            acc += hrel[(size_t)b * H_ + k] * w[(size_t)k * T_ + jl];
        red[kq][jl] = acc;
    }
    __syncthreads();
    if (kq == 0 && jl < T_) {
        float s = bias[jl];
#pragma unroll
        for (int q = 0; q < 8; ++q) s += red[q][jl];
        out[(size_t)b * T_ + jl] = s;
    }
}

extern "C" void kernel_launch(void* const* d_in, const int* in_sizes, int n_in,
                              void* d_out, int out_size, void* d_ws, size_t ws_size,
                              hipStream_t stream) {
    const int*   ids       = (const int*)d_in[0];
    const float* embed     = (const float*)d_in[1];
    const float* in_proj_w = (const float*)d_in[2];
    const float* conv_w    = (const float*)d_in[3];
    const float* conv_b    = (const float*)d_in[4];
    const float* x_proj_w  = (const float*)d_in[5];
    const float* dt_w      = (const float*)d_in[6];
    const float* dt_b      = (const float*)d_in[7];
    const float* A_log     = (const float*)d_in[8];
    const float* D_p       = (const float*)d_in[9];
    const float* out_w     = (const float*)d_in[10];
    const float* norm_w    = (const float*)d_in[11];
    const float* norm_f_w  = (const float*)d_in[12];
    const float* top_w     = (const float*)d_in[13];
    const float* top_b     = (const float*)d_in[14];
    const float* bot_w     = (const float*)d_in[15];
    const float* bot_b     = (const float*)d_in[16];
    float* out = (float*)d_out;

    // workspace layout
    float* ws = (float*)d_ws;
    float* h    = ws;                         // 2048*768
    float* xz   = h + (size_t)BT_ * DM;       // 2048*3072
    float* xc   = xz + (size_t)BT_ * 2 * E_;  // 2048*1536
    float* proj = xc + (size_t)BT_ * E_;      // 2048*80
    float* dtT  = proj + (size_t)BT_ * 80;    // 2048*1536 ([b][e][t])
    float* dxT  = dtT + (size_t)BT_ * E_;
    float* xdT  = dxT + (size_t)BT_ * E_;
    float* zsT  = xdT + (size_t)BT_ * E_;
    float* cls  = zsT + (size_t)BT_ * E_;     // 4*768
    float* hrel = cls + (size_t)B_ * DM;      // 4*1536
    unsigned short* us = (unsigned short*)(hrel + (size_t)B_ * H_);
    unsigned short* xi_h = us;                              // 2048*768
    unsigned short* xi_l = xi_h + (size_t)BT_ * DM;
    unsigned short* yz_h = xi_l + (size_t)BT_ * DM;         // 2048*1536
    unsigned short* yz_l = yz_h + (size_t)BT_ * E_;
    unsigned short* wA_h = yz_l + (size_t)BT_ * E_;         // 3072*768
    unsigned short* wA_l = wA_h + (size_t)(2 * E_) * DM;
    unsigned short* wB_h = wA_l + (size_t)(2 * E_) * DM;    // 768*1536
    unsigned short* wB_l = wB_h + (size_t)DM * E_;

    k_embed<<<BT_, 256, 0, stream>>>(ids, embed, h);

    for (int i = 0; i < NL_; ++i) {
        const float* ipw = in_proj_w + (size_t)i * DM * 2 * E_;
        const float* cwi = conv_w + (size_t)i * E_ * K_;
        const float* cbi = conv_b + (size_t)i * E_;
        const float* xpw = x_proj_w + (size_t)i * E_ * (R_ + 2 * N_);
        const float* dwi = dt_w + (size_t)i * R_ * E_;
        const float* dbi = dt_b + (size_t)i * E_;
        const float* ali = A_log + (size_t)i * E_ * N_;
        const float* dpi = D_p + (size_t)i * E_;
        const float* owi = out_w + (size_t)i * E_ * DM;
        const float* nwi = norm_w + (size_t)i * DM;

        k_rmsnorm<true><<<BT_, 256, 0, stream>>>(h, DM, nwi, nullptr, xi_h, xi_l);
        // in_proj_w [768][3072] -> wA [3072][768] hi/lo
        k_wsplit<<<dim3(2 * E_ / 32, DM / 32), 256, 0, stream>>>(ipw, wA_h, wA_l, DM, 2 * E_);
        // xz[2048][3072] = xi @ in_proj  (MFMA bf16x2)
        k_mmf<128, 128, 64, 64, false><<<dim3(2 * E_ / 128, BT_ / 128), 256, 0, stream>>>(
            xi_h, xi_l, wA_h, wA_l, xz, BT_, 2 * E_, DM);
        k_conv<<<BT_ * E_ / 256, 256, 0, stream>>>(xz, cwi, cbi, xc);
        k_xproj<<<BT_ / 4, 128, 0, stream>>>(xc, xpw, proj);
        k_prep<<<dim3(L_ / 64, E_ / 64, B_), 256, 0, stream>>>(
            proj, dwi, dbi, xc, xz, dpi, dtT, dxT, xdT, zsT);
        k_scan2<<<B_ * E_, 256, 0, stream>>>(dtT, dxT, xdT, zsT, proj, ali, yz_h, yz_l);
        // out_w [1536][768] -> wB [768][1536] hi/lo
        k_wsplit<<<dim3(DM / 32, E_ / 32), 256, 0, stream>>>(owi, wB_h, wB_l, E_, DM);
        // h += yz @ out_w  (MFMA bf16x2, accumulate)
        k_mmf<64, 64, 32, 32, true><<<dim3(DM / 64, BT_ / 64), 256, 0, stream>>>(
            yz_h, yz_l, wB_h, wB_l, h, BT_, DM, E_);
    }

    k_rmsnorm<false><<<B_, 256, 0, stream>>>(h + (size_t)(L_ - 1) * DM, (long)L_ * DM,
                                             norm_f_w, cls, nullptr, nullptr);
    k_top<<<H_ / 64, 256, 0, stream>>>(cls, top_w, top_b, hrel);
    k_bot<<<B_, 256, 0, stream>>>(hrel, bot_w, bot_b, out);
}

// Round 7
// 1567.542 us; speedup vs baseline: 2.2947x; 1.3335x over previous
//
#include <hip/hip_runtime.h>
#include <hip/hip_bf16.h>
#include <math.h>

// Problem constants
#define B_ 4
#define L_ 512
#define DM 768
#define E_ 1536
#define N_ 16
#define R_ 48
#define K_ 4
#define NL_ 4
#define H_ 1536
#define T_ 28
#define BT_ (B_ * L_)   // 2048 tokens
#define PJ 80           // R_ + 2*N_

typedef __bf16 bf16x8 __attribute__((ext_vector_type(8)));
typedef float  f32x4  __attribute__((ext_vector_type(4)));

__device__ __forceinline__ float sigmoidf_(float v) { return 1.0f / (1.0f + expf(-v)); }
__device__ __forceinline__ float siluf_(float v) { return v * sigmoidf_(v); }
__device__ __forceinline__ float softplusf_(float v) {
    return fmaxf(v, 0.0f) + log1pf(expf(-fabsf(v)));
}
__device__ __forceinline__ unsigned short f2bf(float x) {
    unsigned u = __float_as_uint(x);
    u = u + 0x7fffu + ((u >> 16) & 1u);
    return (unsigned short)(u >> 16);
}
__device__ __forceinline__ float bf2f(unsigned short h) {
    return __uint_as_float(((unsigned)h) << 16);
}
__device__ __forceinline__ void gl_lds16(const void* g, void* l) {
    auto gp = reinterpret_cast<const __attribute__((address_space(1))) unsigned int*>(
        reinterpret_cast<uintptr_t>(g));
    auto lp = reinterpret_cast<__attribute__((address_space(3))) unsigned int*>(
        reinterpret_cast<uintptr_t>(l));
    __builtin_amdgcn_global_load_lds(gp, lp, 16, 0, 0);
}

// ---------------- embed gather ----------------
__global__ __launch_bounds__(256) void k_embed(const int* __restrict__ ids,
                                               const float* __restrict__ embed,
                                               float* __restrict__ h) {
    int bt = blockIdx.x;
    int tok = ids[bt];
    const float* src = embed + (size_t)tok * DM;
    float* dst = h + (size_t)bt * DM;
    for (int c = threadIdx.x; c < DM; c += 256) dst[c] = src[c];
}

// ---------------- RMSNorm; BF=true emits bf16 hi/lo split ----------------
template <bool BF>
__global__ __launch_bounds__(256) void k_rmsnorm(const float* __restrict__ base, long rstride,
                                                 const float* __restrict__ w,
                                                 float* __restrict__ outf,
                                                 unsigned short* __restrict__ oh,
                                                 unsigned short* __restrict__ ol) {
    int tid = threadIdx.x;
    const float* row = base + (size_t)blockIdx.x * rstride;
    float v0 = row[tid], v1 = row[tid + 256], v2 = row[tid + 512];
    float s = v0 * v0 + v1 * v1 + v2 * v2;
#pragma unroll
    for (int m = 1; m < 64; m <<= 1) s += __shfl_xor(s, m);
    __shared__ float red[4];
    if ((tid & 63) == 0) red[tid >> 6] = s;
    __syncthreads();
    s = red[0] + red[1] + red[2] + red[3];
    float rs = rsqrtf(s * (1.0f / (float)DM) + 1e-5f);
    float r0 = v0 * rs * w[tid];
    float r1 = v1 * rs * w[tid + 256];
    float r2 = v2 * rs * w[tid + 512];
    size_t o = (size_t)blockIdx.x * DM;
    if (BF) {
        unsigned short h0 = f2bf(r0), h1 = f2bf(r1), h2 = f2bf(r2);
        oh[o + tid] = h0;        ol[o + tid] = f2bf(r0 - bf2f(h0));
        oh[o + tid + 256] = h1;  ol[o + tid + 256] = f2bf(r1 - bf2f(h1));
        oh[o + tid + 512] = h2;  ol[o + tid + 512] = f2bf(r2 - bf2f(h2));
    } else {
        outf[o + tid] = r0;
        outf[o + tid + 256] = r1;
        outf[o + tid + 512] = r2;
    }
}

// ---------------- weight transpose + split: w[K][N] -> wT_hi/lo[N][K] (32x32 tiles) -----------
__global__ __launch_bounds__(256) void k_wsplit(const float* __restrict__ w,
                                                unsigned short* __restrict__ th,
                                                unsigned short* __restrict__ tl,
                                                int K, int N) {
    __shared__ float t[32][33];
    int n0 = blockIdx.x * 32, k0 = blockIdx.y * 32;
    int c = threadIdx.x & 31, r0 = threadIdx.x >> 5;
#pragma unroll
    for (int it = 0; it < 4; ++it) {
        int r = r0 + it * 8;
        t[r][c] = w[(size_t)(k0 + r) * N + n0 + c];
    }
    __syncthreads();
#pragma unroll
    for (int it = 0; it < 4; ++it) {
        int r = r0 + it * 8;
        float v = t[c][r];
        unsigned short h = f2bf(v);
        th[(size_t)(n0 + r) * K + k0 + c] = h;
        tl[(size_t)(n0 + r) * K + k0 + c] = f2bf(v - bf2f(h));
    }
}

// ---------------- x_proj weight: w[1536][80] -> wX_hi/lo[80][1536] ----------------
__global__ __launch_bounds__(256) void k_wsplitX(const float* __restrict__ w,
                                                 unsigned short* __restrict__ th,
                                                 unsigned short* __restrict__ tl) {
    __shared__ float t[16][PJ];
    int k0 = blockIdx.x * 16;
    for (int i = threadIdx.x; i < 16 * PJ; i += 256)
        t[i / PJ][i % PJ] = w[(size_t)(k0 + i / PJ) * PJ + i % PJ];
    __syncthreads();
    for (int i = threadIdx.x; i < 16 * PJ; i += 256) {
        int j = i >> 4, kk = i & 15;     // j<80, kk<16
        float v = t[kk][j];
        unsigned short h = f2bf(v);
        th[(size_t)j * E_ + k0 + kk] = h;
        tl[(size_t)j * E_ + k0 + kk] = f2bf(v - bf2f(h));
    }
}

// ---------------- MFMA GEMM (bf16x2 split): C (+)= A[M,K] @ BT[N,K]^T ----------------
// 256 threads = 4 waves arranged WR x WC; wave tile (BM/WR) x (BN/WC); K-step 32.
// KS>1: grid.z splits K; block kz writes partial C at C + kz*M*N (ACCUM must be false).
template <int BM, int BN, int WR, int WC, bool ACCUM, int KS>
__global__ __launch_bounds__(256) void k_mmf(const unsigned short* __restrict__ Ah,
                                             const unsigned short* __restrict__ Al,
                                             const unsigned short* __restrict__ Bh,
                                             const unsigned short* __restrict__ Bl,
                                             float* __restrict__ C,
                                             int M, int N, int K) {
    constexpr int WM = BM / WR, WN = BN / WC;
    constexpr int MR = WM / 16, NR = WN / 16;
    constexpr int CA = 4 * BM, CB = 4 * BN;
    constexpr int RA = (CA + 255) / 256, RB = (CB + 255) / 256;
    __shared__ __align__(16) unsigned short sAh[CA * 8], sAl[CA * 8];
    __shared__ __align__(16) unsigned short sBh[CB * 8], sBl[CB * 8];
    int tid = threadIdx.x;
    int lane = tid & 63;
    int w = tid >> 6;
    int wr = w / WC, wc = w % WC;
    int m0 = blockIdx.y * BM, n0 = blockIdx.x * BN;
    int kz = (KS > 1) ? blockIdx.z : 0;
    int kb = kz * (K / KS), ke = kb + K / KS;

    f32x4 acc[MR][NR] = {};

    for (int k0 = kb; k0 < ke; k0 += 32) {
#pragma unroll
        for (int r = 0; r < RA; ++r) {
            int cell = (r * 4 + w) * 64 + lane;
            if (CA % 256 == 0 || cell < CA) {
                int oct = cell / BM, row = cell % BM;
                size_t go = (size_t)(m0 + row) * K + k0 + oct * 8;
                gl_lds16(Ah + go, &sAh[(size_t)cell * 8]);
                gl_lds16(Al + go, &sAl[(size_t)cell * 8]);
            }
        }
#pragma unroll
        for (int r = 0; r < RB; ++r) {
            int cell = (r * 4 + w) * 64 + lane;
            if (CB % 256 == 0 || cell < CB) {
                int oct = cell / BN, row = cell % BN;
                size_t go = (size_t)(n0 + row) * K + k0 + oct * 8;
                gl_lds16(Bh + go, &sBh[(size_t)cell * 8]);
                gl_lds16(Bl + go, &sBl[(size_t)cell * 8]);
            }
        }
        asm volatile("s_waitcnt vmcnt(0)" ::: "memory");
        __syncthreads();

        int oct = lane >> 4;
        int rl = lane & 15;
        bf16x8 ah[MR], al[MR], bh[NR], bl[NR];
#pragma unroll
        for (int i = 0; i < MR; ++i) {
            int row = wr * WM + i * 16 + rl;
            ah[i] = *(const bf16x8*)&sAh[(oct * BM + row) * 8];
            al[i] = *(const bf16x8*)&sAl[(oct * BM + row) * 8];
        }
#pragma unroll
        for (int j = 0; j < NR; ++j) {
            int row = wc * WN + j * 16 + rl;
            bh[j] = *(const bf16x8*)&sBh[(oct * BN + row) * 8];
            bl[j] = *(const bf16x8*)&sBl[(oct * BN + row) * 8];
        }
#pragma unroll
        for (int i = 0; i < MR; ++i)
#pragma unroll
            for (int j = 0; j < NR; ++j) {
                acc[i][j] = __builtin_amdgcn_mfma_f32_16x16x32_bf16(ah[i], bh[j], acc[i][j], 0, 0, 0);
                acc[i][j] = __builtin_amdgcn_mfma_f32_16x16x32_bf16(ah[i], bl[j], acc[i][j], 0, 0, 0);
                acc[i][j] = __builtin_amdgcn_mfma_f32_16x16x32_bf16(al[i], bh[j], acc[i][j], 0, 0, 0);
            }
        __syncthreads();
    }
    float* Cw = C + (size_t)kz * M * N;
    int rl = lane & 15, rq = lane >> 4;
#pragma unroll
    for (int i = 0; i < MR; ++i)
#pragma unroll
        for (int j = 0; j < NR; ++j)
#pragma unroll
            for (int v = 0; v < 4; ++v) {
                int row = m0 + wr * WM + i * 16 + rq * 4 + v;
                int col = n0 + wc * WN + j * 16 + rl;
                float val = acc[i][j][v];
                if (ACCUM) val += Cw[(size_t)row * N + col];
                Cw[(size_t)row * N + col] = val;
            }
}

// ---------------- K-split partial reduce: proj = sum_{kz} pp[kz] ----------------
__global__ __launch_bounds__(256) void k_padd(const float* __restrict__ pp,
                                              float* __restrict__ proj) {
    int idx = blockIdx.x * 256 + threadIdx.x;
    const int MN = BT_ * PJ;
    if (idx < MN)
        proj[idx] = pp[idx] + pp[MN + idx] + pp[2 * MN + idx] + pp[3 * MN + idx];
}

// ---------------- causal depthwise conv (K=4) + SiLU; emits f32 + bf16 hi/lo ---------------
__global__ __launch_bounds__(256) void k_conv(const float* __restrict__ xz,
                                              const float* __restrict__ cw,
                                              const float* __restrict__ cb,
                                              float* __restrict__ xc,
                                              unsigned short* __restrict__ xch,
                                              unsigned short* __restrict__ xcl) {
    int idx = blockIdx.x * 256 + threadIdx.x;
    int e = idx % E_;
    int bt = idx / E_;
    int t = bt & (L_ - 1);
    const float* base = xz + (size_t)bt * (2 * E_) + e;
    float w0 = cw[e * 4 + 0], w1 = cw[e * 4 + 1], w2 = cw[e * 4 + 2], w3 = cw[e * 4 + 3];
    float acc = cb[e] + base[0] * w3;
    if (t >= 1) acc += base[-(2 * E_)] * w2;
    if (t >= 2) acc += base[-(4 * E_)] * w1;
    if (t >= 3) acc += base[-(6 * E_)] * w0;
    float v = siluf_(acc);
    xc[idx] = v;
    unsigned short hh = f2bf(v);
    xch[idx] = hh;
    xcl[idx] = f2bf(v - bf2f(hh));
}

// ---------------- k_prep: dt GEMM(K=48)+softplus + transposed scan inputs ----------------
__global__ __launch_bounds__(256) void k_prep(const float* __restrict__ proj,
                                              const float* __restrict__ dw,
                                              const float* __restrict__ db,
                                              const float* __restrict__ xc,
                                              const float* __restrict__ xz,
                                              const float* __restrict__ dp,
                                              float* __restrict__ dtT,
                                              float* __restrict__ dxT,
                                              float* __restrict__ xdT,
                                              float* __restrict__ zsT) {
    __shared__ float projS[64][48];
    __shared__ float dwS[48][64];
    __shared__ float tileT[64][65];
    int b = blockIdx.z;
    int t0 = blockIdx.x * 64;
    int e0 = blockIdx.y * 64;
    int tid = threadIdx.x;

    for (int idx = tid; idx < 64 * 48; idx += 256) {
        int tl = idx / 48, k = idx % 48;
        projS[tl][k] = proj[(size_t)(b * L_ + t0 + tl) * PJ + k];
    }
    for (int idx = tid; idx < 48 * 64; idx += 256) {
        int k = idx >> 6, ee = idx & 63;
        dwS[k][ee] = dw[(size_t)k * E_ + e0 + ee];
    }
    __syncthreads();

    int el = tid & 63;
    int tg = tid >> 6;
    float acc[16];
    float bvE = db[e0 + el];
#pragma unroll
    for (int s = 0; s < 16; ++s) acc[s] = bvE;
    for (int k = 0; k < 48; ++k) {
        float wv = dwS[k][el];
#pragma unroll
        for (int s = 0; s < 16; ++s) acc[s] += projS[tg * 16 + s][k] * wv;
    }
    float dtv[16];
#pragma unroll
    for (int s = 0; s < 16; ++s) dtv[s] = softplusf_(acc[s]);
    float xv[16];
#pragma unroll
    for (int s = 0; s < 16; ++s)
        xv[s] = xc[(size_t)(b * L_ + t0 + tg * 16 + s) * E_ + e0 + el];
    float dpv = dp[e0 + el];

#define XPOSE_OUT(dst, EXPR)                                                      \
    do {                                                                          \
        __syncthreads();                                                          \
        for (int s = 0; s < 16; ++s) tileT[el][tg * 16 + s] = (EXPR);             \
        __syncthreads();                                                          \
        for (int idx = tid; idx < 4096; idx += 256) {                             \
            int e2 = idx >> 6, t2 = idx & 63;                                     \
            dst[((size_t)b * E_ + e0 + e2) * L_ + t0 + t2] = tileT[e2][t2];       \
        }                                                                         \
    } while (0)

    XPOSE_OUT(dtT, dtv[s]);
    XPOSE_OUT(dxT, dtv[s] * xv[s]);
    XPOSE_OUT(xdT, xv[s] * dpv);
    float zv[16];
#pragma unroll
    for (int s = 0; s < 16; ++s)
        zv[s] = xz[(size_t)(b * L_ + t0 + tg * 16 + s) * (2 * E_) + E_ + e0 + el];
    XPOSE_OUT(zsT, siluf_(zv[s]));
#undef XPOSE_OUT
}

// ---------------- chunked parallel selective scan; emits yz as bf16 hi/lo ----------------
__global__ __launch_bounds__(256) void k_scan2(const float* __restrict__ dtT,
                                               const float* __restrict__ dxT,
                                               const float* __restrict__ xdT,
                                               const float* __restrict__ zsT,
                                               const float* __restrict__ proj,
                                               const float* __restrict__ A_log,
                                               unsigned short* __restrict__ yzh,
                                               unsigned short* __restrict__ yzl) {
    __shared__ float s_dt[L_], s_xd[L_], s_zs[L_];
    __shared__ float sAP[16][17], sAS[16][17], sH[16][17];
    int tid = threadIdx.x;
    int b = blockIdx.x / E_;
    int e = blockIdx.x - b * E_;
    size_t base = ((size_t)b * E_ + e) * L_;

    for (int idx = tid; idx < L_; idx += 256) {
        s_dt[idx] = dtT[base + idx];
        s_xd[idx] = xdT[base + idx];
        s_zs[idx] = zsT[base + idx];
    }
    int c = tid >> 4;
    int n = tid & 15;
    float A = -expf(A_log[e * N_ + n]);
    __syncthreads();

    int t0 = c * 32;
    const float* pb = proj + (size_t)(b * L_ + t0) * PJ + R_ + n;
    const float* pdx = dxT + base + t0;

    float dAr[32], ur[32];
    float P = 1.0f, S = 0.0f;
#pragma unroll
    for (int s = 0; s < 32; ++s) {
        float dtv = s_dt[t0 + s];
        float dA = expf(dtv * A);
        float u = pdx[s] * pb[s * PJ];
        dAr[s] = dA;
        ur[s] = u;
        P *= dA;
        S = dA * S + u;
    }
    sAP[c][n] = P;
    sAS[c][n] = S;
    __syncthreads();
    if (tid < 16) {
        float H = 0.0f;
        for (int c2 = 0; c2 < 16; ++c2) {
            sH[c2][tid] = H;
            H = sAP[c2][tid] * H + sAS[c2][tid];
        }
    }
    __syncthreads();

    float h = sH[c][n];
    const float* pc = proj + (size_t)(b * L_ + t0) * PJ + R_ + N_ + n;
#pragma unroll
    for (int s = 0; s < 32; ++s) {
        h = dAr[s] * h + ur[s];
        float p = h * pc[s * PJ];
        p += __shfl_xor(p, 1);
        p += __shfl_xor(p, 2);
        p += __shfl_xor(p, 4);
        p += __shfl_xor(p, 8);
        if (n == 0) {
            float v = (p + s_xd[t0 + s]) * s_zs[t0 + s];
            unsigned short hh = f2bf(v);
            size_t oidx = (size_t)(b * L_ + t0 + s) * E_ + e;
            yzh[oidx] = hh;
            yzl[oidx] = f2bf(v - bf2f(hh));
        }
    }
}

// ---------------- head: hrel = relu(cls @ top_w + top_b) ----------------
__global__ __launch_bounds__(256) void k_top(const float* __restrict__ cls,
                                             const float* __restrict__ w,
                                             const float* __restrict__ bias,
                                             float* __restrict__ hrel) {
    __shared__ float xs[B_][DM];
    __shared__ float red[4][64][B_];
    int tid = threadIdx.x;
    for (int c = tid; c < B_ * DM; c += 256) ((float*)xs)[c] = cls[c];
    __syncthreads();
    int jl = tid & 63;
    int kq = tid >> 6;
    int j = blockIdx.x * 64 + jl;
    float acc[B_] = {};
    for (int k = kq * (DM / 4); k < (kq + 1) * (DM / 4); ++k) {
        float wv = w[(size_t)k * H_ + j];
#pragma unroll
        for (int b = 0; b < B_; ++b) acc[b] += xs[b][k] * wv;
    }
#pragma unroll
    for (int b = 0; b < B_; ++b) red[kq][jl][b] = acc[b];
    __syncthreads();
    if (kq == 0) {
        float bv = bias[j];
#pragma unroll
        for (int b = 0; b < B_; ++b) {
            float s = red[0][jl][b] + red[1][jl][b] + red[2][jl][b] + red[3][jl][b] + bv;
            hrel[(size_t)b * H_ + j] = fmaxf(s, 0.0f);
        }
    }
}

// ---------------- head: out = hrel @ bot_w + bot_b ----------------
__global__ __launch_bounds__(256) void k_bot(const float* __restrict__ hrel,
                                             const float* __restrict__ w,
                                             const float* __restrict__ bias,
                                             float* __restrict__ out) {
    __shared__ float red[8][T_];
    int b = blockIdx.x;
    int jl = threadIdx.x & 31;
    int kq = threadIdx.x >> 5;
    if (jl < T_) {
        float acc = 0.0f;
        for (int k = kq * (H_ / 8); k < (kq + 1) * (H_ / 8); ++k)
            acc += hrel[(size_t)b * H_ + k] * w[(size_t)k * T_ + jl];
        red[kq][jl] = acc;
    }
    __syncthreads();
    if (kq == 0 && jl < T_) {
        float s = bias[jl];
#pragma unroll
        for (int q = 0; q < 8; ++q) s += red[q][jl];
        out[(size_t)b * T_ + jl] = s;
    }
}

extern "C" void kernel_launch(void* const* d_in, const int* in_sizes, int n_in,
                              void* d_out, int out_size, void* d_ws, size_t ws_size,
                              hipStream_t stream) {
    const int*   ids       = (const int*)d_in[0];
    const float* embed     = (const float*)d_in[1];
    const float* in_proj_w = (const float*)d_in[2];
    const float* conv_w    = (const float*)d_in[3];
    const float* conv_b    = (const float*)d_in[4];
    const float* x_proj_w  = (const float*)d_in[5];
    const float* dt_w      = (const float*)d_in[6];
    const float* dt_b      = (const float*)d_in[7];
    const float* A_log     = (const float*)d_in[8];
    const float* D_p       = (const float*)d_in[9];
    const float* out_w     = (const float*)d_in[10];
    const float* norm_w    = (const float*)d_in[11];
    const float* norm_f_w  = (const float*)d_in[12];
    const float* top_w     = (const float*)d_in[13];
    const float* top_b     = (const float*)d_in[14];
    const float* bot_w     = (const float*)d_in[15];
    const float* bot_b     = (const float*)d_in[16];
    float* out = (float*)d_out;

    // workspace layout
    float* ws = (float*)d_ws;
    float* h    = ws;                         // 2048*768
    float* xz   = h + (size_t)BT_ * DM;       // 2048*3072
    float* xc   = xz + (size_t)BT_ * 2 * E_;  // 2048*1536
    float* proj = xc + (size_t)BT_ * E_;      // 2048*80
    float* dtT  = proj + (size_t)BT_ * PJ;    // 2048*1536 ([b][e][t])
    float* dxT  = dtT + (size_t)BT_ * E_;
    float* xdT  = dxT + (size_t)BT_ * E_;
    float* zsT  = xdT + (size_t)BT_ * E_;
    float* cls  = zsT + (size_t)BT_ * E_;     // 4*768
    float* hrel = cls + (size_t)B_ * DM;      // 4*1536
    unsigned short* us = (unsigned short*)(hrel + (size_t)B_ * H_);
    unsigned short* xi_h = us;                              // 2048*768
    unsigned short* xi_l = xi_h + (size_t)BT_ * DM;
    unsigned short* yz_h = xi_l + (size_t)BT_ * DM;         // 2048*1536
    unsigned short* yz_l = yz_h + (size_t)BT_ * E_;
    unsigned short* wA_h = yz_l + (size_t)BT_ * E_;         // 3072*768
    unsigned short* wA_l = wA_h + (size_t)(2 * E_) * DM;
    unsigned short* wB_h = wA_l + (size_t)(2 * E_) * DM;    // 768*1536
    unsigned short* wB_l = wB_h + (size_t)DM * E_;
    unsigned short* xc_h = wB_l + (size_t)DM * E_;          // 2048*1536
    unsigned short* xc_l = xc_h + (size_t)BT_ * E_;
    unsigned short* wX_h = xc_l + (size_t)BT_ * E_;         // 80*1536
    unsigned short* wX_l = wX_h + (size_t)PJ * E_;
    float* pp = (float*)(wX_l + (size_t)PJ * E_);           // 4*2048*80 partials

    k_embed<<<BT_, 256, 0, stream>>>(ids, embed, h);

    for (int i = 0; i < NL_; ++i) {
        const float* ipw = in_proj_w + (size_t)i * DM * 2 * E_;
        const float* cwi = conv_w + (size_t)i * E_ * K_;
        const float* cbi = conv_b + (size_t)i * E_;
        const float* xpw = x_proj_w + (size_t)i * E_ * PJ;
        const float* dwi = dt_w + (size_t)i * R_ * E_;
        const float* dbi = dt_b + (size_t)i * E_;
        const float* ali = A_log + (size_t)i * E_ * N_;
        const float* dpi = D_p + (size_t)i * E_;
        const float* owi = out_w + (size_t)i * E_ * DM;
        const float* nwi = norm_w + (size_t)i * DM;

        k_rmsnorm<true><<<BT_, 256, 0, stream>>>(h, DM, nwi, nullptr, xi_h, xi_l);
        k_wsplit<<<dim3(2 * E_ / 32, DM / 32), 256, 0, stream>>>(ipw, wA_h, wA_l, DM, 2 * E_);
        // xz = xi @ in_proj (MFMA bf16x2): 128x128 tile, 2x2 waves
        k_mmf<128, 128, 2, 2, false, 1><<<dim3(2 * E_ / 128, BT_ / 128), 256, 0, stream>>>(
            xi_h, xi_l, wA_h, wA_l, xz, BT_, 2 * E_, DM);
        k_conv<<<BT_ * E_ / 256, 256, 0, stream>>>(xz, cwi, cbi, xc, xc_h, xc_l);
        // x_proj: proj[2048][80] = xc @ wX^T, K-split 4 + reduce
        k_wsplitX<<<E_ / 16, 256, 0, stream>>>(xpw, wX_h, wX_l);
        k_mmf<128, PJ, 4, 1, false, 4><<<dim3(1, BT_ / 128, 4), 256, 0, stream>>>(
            xc_h, xc_l, wX_h, wX_l, pp, BT_, PJ, E_);
        k_padd<<<(BT_ * PJ + 255) / 256, 256, 0, stream>>>(pp, proj);
        k_prep<<<dim3(L_ / 64, E_ / 64, B_), 256, 0, stream>>>(
            proj, dwi, dbi, xc, xz, dpi, dtT, dxT, xdT, zsT);
        k_scan2<<<B_ * E_, 256, 0, stream>>>(dtT, dxT, xdT, zsT, proj, ali, yz_h, yz_l);
        k_wsplit<<<dim3(DM / 32, E_ / 32), 256, 0, stream>>>(owi, wB_h, wB_l, E_, DM);
        // h += yz @ out_w: 64x64 tile, 2x2 waves
        k_mmf<64, 64, 2, 2, true, 1><<<dim3(DM / 64, BT_ / 64), 256, 0, stream>>>(
            yz_h, yz_l, wB_h, wB_l, h, BT_, DM, E_);
    }

    k_rmsnorm<false><<<B_, 256, 0, stream>>>(h + (size_t)(L_ - 1) * DM, (long)L_ * DM,
                                             norm_f_w, cls, nullptr, nullptr);
    k_top<<<H_ / 64, 256, 0, stream>>>(cls, top_w, top_b, hrel);
    k_bot<<<B_, 256, 0, stream>>>(hrel, bot_w, bot_b, out);
}

// Round 8
// 1517.668 us; speedup vs baseline: 2.3701x; 1.0329x over previous
//
#include <hip/hip_runtime.h>
#include <hip/hip_bf16.h>
#include <math.h>

// Problem constants
#define B_ 4
#define L_ 512
#define DM 768
#define E_ 1536
#define N_ 16
#define R_ 48
#define K_ 4
#define NL_ 4
#define H_ 1536
#define T_ 28
#define BT_ (B_ * L_)   // 2048 tokens
#define PJ 80           // R_ + 2*N_

typedef __bf16 bf16x8 __attribute__((ext_vector_type(8)));
typedef float  f32x4  __attribute__((ext_vector_type(4)));

__device__ __forceinline__ float sigmoidf_(float v) { return 1.0f / (1.0f + expf(-v)); }
__device__ __forceinline__ float siluf_(float v) { return v * sigmoidf_(v); }
__device__ __forceinline__ float softplusf_(float v) {
    return fmaxf(v, 0.0f) + log1pf(expf(-fabsf(v)));
}
__device__ __forceinline__ unsigned short f2bf(float x) {
    unsigned u = __float_as_uint(x);
    u = u + 0x7fffu + ((u >> 16) & 1u);
    return (unsigned short)(u >> 16);
}
__device__ __forceinline__ float bf2f(unsigned short h) {
    return __uint_as_float(((unsigned)h) << 16);
}
__device__ __forceinline__ void gl_lds16(const void* g, void* l) {
    auto gp = reinterpret_cast<const __attribute__((address_space(1))) unsigned int*>(
        reinterpret_cast<uintptr_t>(g));
    auto lp = reinterpret_cast<__attribute__((address_space(3))) unsigned int*>(
        reinterpret_cast<uintptr_t>(l));
    __builtin_amdgcn_global_load_lds(gp, lp, 16, 0, 0);
}

// ---------------- embed gather ----------------
__global__ __launch_bounds__(256) void k_embed(const int* __restrict__ ids,
                                               const float* __restrict__ embed,
                                               float* __restrict__ h) {
    int bt = blockIdx.x;
    int tok = ids[bt];
    const float* src = embed + (size_t)tok * DM;
    float* dst = h + (size_t)bt * DM;
    for (int c = threadIdx.x; c < DM; c += 256) dst[c] = src[c];
}

// ---------------- RMSNorm; BF=true emits bf16 hi/lo split ----------------
template <bool BF>
__global__ __launch_bounds__(256) void k_rmsnorm(const float* __restrict__ base, long rstride,
                                                 const float* __restrict__ w,
                                                 float* __restrict__ outf,
                                                 unsigned short* __restrict__ oh,
                                                 unsigned short* __restrict__ ol) {
    int tid = threadIdx.x;
    const float* row = base + (size_t)blockIdx.x * rstride;
    float v0 = row[tid], v1 = row[tid + 256], v2 = row[tid + 512];
    float s = v0 * v0 + v1 * v1 + v2 * v2;
#pragma unroll
    for (int m = 1; m < 64; m <<= 1) s += __shfl_xor(s, m);
    __shared__ float red[4];
    if ((tid & 63) == 0) red[tid >> 6] = s;
    __syncthreads();
    s = red[0] + red[1] + red[2] + red[3];
    float rs = rsqrtf(s * (1.0f / (float)DM) + 1e-5f);
    float r0 = v0 * rs * w[tid];
    float r1 = v1 * rs * w[tid + 256];
    float r2 = v2 * rs * w[tid + 512];
    size_t o = (size_t)blockIdx.x * DM;
    if (BF) {
        unsigned short h0 = f2bf(r0), h1 = f2bf(r1), h2 = f2bf(r2);
        oh[o + tid] = h0;        ol[o + tid] = f2bf(r0 - bf2f(h0));
        oh[o + tid + 256] = h1;  ol[o + tid + 256] = f2bf(r1 - bf2f(h1));
        oh[o + tid + 512] = h2;  ol[o + tid + 512] = f2bf(r2 - bf2f(h2));
    } else {
        outf[o + tid] = r0;
        outf[o + tid + 256] = r1;
        outf[o + tid + 512] = r2;
    }
}

// ---------------- weight transpose + split: w[K][N] -> wT_hi/lo[N][K] (32x32 tiles) -----------
__global__ __launch_bounds__(256) void k_wsplit(const float* __restrict__ w,
                                                unsigned short* __restrict__ th,
                                                unsigned short* __restrict__ tl,
                                                int K, int N) {
    __shared__ float t[32][33];
    int n0 = blockIdx.x * 32, k0 = blockIdx.y * 32;
    int c = threadIdx.x & 31, r0 = threadIdx.x >> 5;
#pragma unroll
    for (int it = 0; it < 4; ++it) {
        int r = r0 + it * 8;
        t[r][c] = w[(size_t)(k0 + r) * N + n0 + c];
    }
    __syncthreads();
#pragma unroll
    for (int it = 0; it < 4; ++it) {
        int r = r0 + it * 8;
        float v = t[c][r];
        unsigned short h = f2bf(v);
        th[(size_t)(n0 + r) * K + k0 + c] = h;
        tl[(size_t)(n0 + r) * K + k0 + c] = f2bf(v - bf2f(h));
    }
}

// ---------------- x_proj weight: w[1536][80] -> wX_hi/lo[80][1536] ----------------
__global__ __launch_bounds__(256) void k_wsplitX(const float* __restrict__ w,
                                                 unsigned short* __restrict__ th,
                                                 unsigned short* __restrict__ tl) {
    __shared__ float t[16][PJ];
    int k0 = blockIdx.x * 16;
    for (int i = threadIdx.x; i < 16 * PJ; i += 256)
        t[i / PJ][i % PJ] = w[(size_t)(k0 + i / PJ) * PJ + i % PJ];
    __syncthreads();
    for (int i = threadIdx.x; i < 16 * PJ; i += 256) {
        int j = i >> 4, kk = i & 15;     // j<80, kk<16
        float v = t[kk][j];
        unsigned short h = f2bf(v);
        th[(size_t)j * E_ + k0 + kk] = h;
        tl[(size_t)j * E_ + k0 + kk] = f2bf(v - bf2f(h));
    }
}

// ---------------- MFMA GEMM (bf16x2 split): C (+)= A[M,K] @ BT[N,K]^T ----------------
// 256 threads = 4 waves arranged WR x WC; wave tile (BM/WR) x (BN/WC); K-step 32.
// KS>1: grid.z splits K; block kz writes partial C at C + kz*M*N (ACCUM must be false).
template <int BM, int BN, int WR, int WC, bool ACCUM, int KS>
__global__ __launch_bounds__(256) void k_mmf(const unsigned short* __restrict__ Ah,
                                             const unsigned short* __restrict__ Al,
                                             const unsigned short* __restrict__ Bh,
                                             const unsigned short* __restrict__ Bl,
                                             float* __restrict__ C,
                                             int M, int N, int K) {
    constexpr int WM = BM / WR, WN = BN / WC;
    constexpr int MR = WM / 16, NR = WN / 16;
    constexpr int CA = 4 * BM, CB = 4 * BN;
    constexpr int RA = (CA + 255) / 256, RB = (CB + 255) / 256;
    __shared__ __align__(16) unsigned short sAh[CA * 8], sAl[CA * 8];
    __shared__ __align__(16) unsigned short sBh[CB * 8], sBl[CB * 8];
    int tid = threadIdx.x;
    int lane = tid & 63;
    int w = tid >> 6;
    int wr = w / WC, wc = w % WC;
    int m0 = blockIdx.y * BM, n0 = blockIdx.x * BN;
    int kz = (KS > 1) ? blockIdx.z : 0;
    int kb = kz * (K / KS), ke = kb + K / KS;

    f32x4 acc[MR][NR] = {};

    for (int k0 = kb; k0 < ke; k0 += 32) {
#pragma unroll
        for (int r = 0; r < RA; ++r) {
            int cell = (r * 4 + w) * 64 + lane;
            if (CA % 256 == 0 || cell < CA) {
                int oct = cell / BM, row = cell % BM;
                size_t go = (size_t)(m0 + row) * K + k0 + oct * 8;
                gl_lds16(Ah + go, &sAh[(size_t)cell * 8]);
                gl_lds16(Al + go, &sAl[(size_t)cell * 8]);
            }
        }
#pragma unroll
        for (int r = 0; r < RB; ++r) {
            int cell = (r * 4 + w) * 64 + lane;
            if (CB % 256 == 0 || cell < CB) {
                int oct = cell / BN, row = cell % BN;
                size_t go = (size_t)(n0 + row) * K + k0 + oct * 8;
                gl_lds16(Bh + go, &sBh[(size_t)cell * 8]);
                gl_lds16(Bl + go, &sBl[(size_t)cell * 8]);
            }
        }
        asm volatile("s_waitcnt vmcnt(0)" ::: "memory");
        __syncthreads();

        int oct = lane >> 4;
        int rl = lane & 15;
        bf16x8 ah[MR], al[MR], bh[NR], bl[NR];
#pragma unroll
        for (int i = 0; i < MR; ++i) {
            int row = wr * WM + i * 16 + rl;
            ah[i] = *(const bf16x8*)&sAh[(oct * BM + row) * 8];
            al[i] = *(const bf16x8*)&sAl[(oct * BM + row) * 8];
        }
#pragma unroll
        for (int j = 0; j < NR; ++j) {
            int row = wc * WN + j * 16 + rl;
            bh[j] = *(const bf16x8*)&sBh[(oct * BN + row) * 8];
            bl[j] = *(const bf16x8*)&sBl[(oct * BN + row) * 8];
        }
#pragma unroll
        for (int i = 0; i < MR; ++i)
#pragma unroll
            for (int j = 0; j < NR; ++j) {
                acc[i][j] = __builtin_amdgcn_mfma_f32_16x16x32_bf16(ah[i], bh[j], acc[i][j], 0, 0, 0);
                acc[i][j] = __builtin_amdgcn_mfma_f32_16x16x32_bf16(ah[i], bl[j], acc[i][j], 0, 0, 0);
                acc[i][j] = __builtin_amdgcn_mfma_f32_16x16x32_bf16(al[i], bh[j], acc[i][j], 0, 0, 0);
            }
        __syncthreads();
    }
    float* Cw = C + (size_t)kz * M * N;
    int rl = lane & 15, rq = lane >> 4;
#pragma unroll
    for (int i = 0; i < MR; ++i)
#pragma unroll
        for (int j = 0; j < NR; ++j)
#pragma unroll
            for (int v = 0; v < 4; ++v) {
                int row = m0 + wr * WM + i * 16 + rq * 4 + v;
                int col = n0 + wc * WN + j * 16 + rl;
                float val = acc[i][j][v];
                if (ACCUM) val += Cw[(size_t)row * N + col];
                Cw[(size_t)row * N + col] = val;
            }
}

// ---------------- K-split partial reduce: proj = sum_{kz} pp[kz] ----------------
__global__ __launch_bounds__(256) void k_padd(const float* __restrict__ pp,
                                              float* __restrict__ proj) {
    int idx = blockIdx.x * 256 + threadIdx.x;
    const int MN = BT_ * PJ;
    if (idx < MN)
        proj[idx] = pp[idx] + pp[MN + idx] + pp[2 * MN + idx] + pp[3 * MN + idx];
}

// ---------------- causal depthwise conv (K=4) + SiLU; emits f32 + bf16 hi/lo ---------------
__global__ __launch_bounds__(256) void k_conv(const float* __restrict__ xz,
                                              const float* __restrict__ cw,
                                              const float* __restrict__ cb,
                                              float* __restrict__ xc,
                                              unsigned short* __restrict__ xch,
                                              unsigned short* __restrict__ xcl) {
    int idx = blockIdx.x * 256 + threadIdx.x;
    int e = idx % E_;
    int bt = idx / E_;
    int t = bt & (L_ - 1);
    const float* base = xz + (size_t)bt * (2 * E_) + e;
    float w0 = cw[e * 4 + 0], w1 = cw[e * 4 + 1], w2 = cw[e * 4 + 2], w3 = cw[e * 4 + 3];
    float acc = cb[e] + base[0] * w3;
    if (t >= 1) acc += base[-(2 * E_)] * w2;
    if (t >= 2) acc += base[-(4 * E_)] * w1;
    if (t >= 3) acc += base[-(6 * E_)] * w0;
    float v = siluf_(acc);
    xc[idx] = v;
    unsigned short hh = f2bf(v);
    xch[idx] = hh;
    xcl[idx] = f2bf(v - bf2f(hh));
}

// ---------------- k_prep: dt GEMM(K=48)+softplus + transposed scan inputs ----------------
__global__ __launch_bounds__(256) void k_prep(const float* __restrict__ proj,
                                              const float* __restrict__ dw,
                                              const float* __restrict__ db,
                                              const float* __restrict__ xc,
                                              const float* __restrict__ xz,
                                              const float* __restrict__ dp,
                                              float* __restrict__ dtT,
                                              float* __restrict__ dxT,
                                              float* __restrict__ xdT,
                                              float* __restrict__ zsT) {
    __shared__ float projS[64][48];
    __shared__ float dwS[48][64];
    __shared__ float tileT[64][65];
    int b = blockIdx.z;
    int t0 = blockIdx.x * 64;
    int e0 = blockIdx.y * 64;
    int tid = threadIdx.x;

    for (int idx = tid; idx < 64 * 48; idx += 256) {
        int tl = idx / 48, k = idx % 48;
        projS[tl][k] = proj[(size_t)(b * L_ + t0 + tl) * PJ + k];
    }
    for (int idx = tid; idx < 48 * 64; idx += 256) {
        int k = idx >> 6, ee = idx & 63;
        dwS[k][ee] = dw[(size_t)k * E_ + e0 + ee];
    }
    __syncthreads();

    int el = tid & 63;
    int tg = tid >> 6;
    float acc[16];
    float bvE = db[e0 + el];
#pragma unroll
    for (int s = 0; s < 16; ++s) acc[s] = bvE;
    for (int k = 0; k < 48; ++k) {
        float wv = dwS[k][el];
#pragma unroll
        for (int s = 0; s < 16; ++s) acc[s] += projS[tg * 16 + s][k] * wv;
    }
    float dtv[16];
#pragma unroll
    for (int s = 0; s < 16; ++s) dtv[s] = softplusf_(acc[s]);
    float xv[16];
#pragma unroll
    for (int s = 0; s < 16; ++s)
        xv[s] = xc[(size_t)(b * L_ + t0 + tg * 16 + s) * E_ + e0 + el];
    float dpv = dp[e0 + el];

#define XPOSE_OUT(dst, EXPR)                                                      \
    do {                                                                          \
        __syncthreads();                                                          \
        for (int s = 0; s < 16; ++s) tileT[el][tg * 16 + s] = (EXPR);             \
        __syncthreads();                                                          \
        for (int idx = tid; idx < 4096; idx += 256) {                             \
            int e2 = idx >> 6, t2 = idx & 63;                                     \
            dst[((size_t)b * E_ + e0 + e2) * L_ + t0 + t2] = tileT[e2][t2];       \
        }                                                                         \
    } while (0)

    XPOSE_OUT(dtT, dtv[s]);
    XPOSE_OUT(dxT, dtv[s] * xv[s]);
    XPOSE_OUT(xdT, xv[s] * dpv);
    float zv[16];
#pragma unroll
    for (int s = 0; s < 16; ++s)
        zv[s] = xz[(size_t)(b * L_ + t0 + tg * 16 + s) * (2 * E_) + E_ + e0 + el];
    XPOSE_OUT(zsT, siluf_(zv[s]));
#undef XPOSE_OUT
}

// ---------------- chunked parallel selective scan -> yzT f32 [b][e][t] ----------------
// LDS padded via t -> t + (t>>5) to kill 4-way chunk-base bank conflicts.
// Output buffered in LDS, then one coalesced block-private row write (no write amp).
// NOTE: yzT may alias dxT (all dxT reads complete before the final barrier; regions
// are per-(b,e) disjoint) — so these two params are NOT __restrict__.
__global__ __launch_bounds__(256) void k_scan2(const float* __restrict__ dtT,
                                               const float* dxT,
                                               const float* __restrict__ xdT,
                                               const float* __restrict__ zsT,
                                               const float* __restrict__ proj,
                                               const float* __restrict__ A_log,
                                               float* yzT) {
    __shared__ float s_dt[528], s_xd[528], s_zs[528], s_y[528];
    __shared__ float sAP[16][17], sAS[16][17], sH[16][17];
    int tid = threadIdx.x;
    int b = blockIdx.x / E_;
    int e = blockIdx.x - b * E_;
    size_t base = ((size_t)b * E_ + e) * L_;

    for (int idx = tid; idx < L_; idx += 256) {
        int ti = idx + (idx >> 5);
        s_dt[ti] = dtT[base + idx];
        s_xd[ti] = xdT[base + idx];
        s_zs[ti] = zsT[base + idx];
    }
    int c = tid >> 4;
    int n = tid & 15;
    float A = -expf(A_log[e * N_ + n]);
    __syncthreads();

    int t0 = c * 32;
    int l0 = c * 33;   // padded base
    const float* pb = proj + (size_t)(b * L_ + t0) * PJ + R_ + n;
    const float* pdx = dxT + base + t0;

    // phase 1: per-chunk (P, S) with dA,u cached in registers
    float dAr[32], ur[32];
    float P = 1.0f, S = 0.0f;
#pragma unroll
    for (int s = 0; s < 32; ++s) {
        float dtv = s_dt[l0 + s];
        float dA = expf(dtv * A);
        float u = pdx[s] * pb[s * PJ];
        dAr[s] = dA;
        ur[s] = u;
        P *= dA;
        S = dA * S + u;
    }
    sAP[c][n] = P;
    sAS[c][n] = S;
    __syncthreads();
    if (tid < 16) {
        float Hc = 0.0f;
        for (int c2 = 0; c2 < 16; ++c2) {
            sH[c2][tid] = Hc;
            Hc = sAP[c2][tid] * Hc + sAS[c2][tid];
        }
    }
    __syncthreads();

    // phase 2: replay; stash y-dot in LDS (bank-spread via l0)
    float h = sH[c][n];
    const float* pc = proj + (size_t)(b * L_ + t0) * PJ + R_ + N_ + n;
#pragma unroll
    for (int s = 0; s < 32; ++s) {
        h = dAr[s] * h + ur[s];
        float p = h * pc[s * PJ];
        p += __shfl_xor(p, 1);
        p += __shfl_xor(p, 2);
        p += __shfl_xor(p, 4);
        p += __shfl_xor(p, 8);
        if (n == 0) s_y[l0 + s] = p;
    }
    __syncthreads();
    // coalesced block-private output row
    for (int idx = tid; idx < L_; idx += 256) {
        int ti = idx + (idx >> 5);
        yzT[base + idx] = (s_y[ti] + s_xd[ti]) * s_zs[ti];
    }
}

// ---------------- yzT [b][e][t] f32 -> yz_h/yz_l [bt][e] bf16 (64x64 LDS transpose) --------
__global__ __launch_bounds__(256) void k_ytr(const float* __restrict__ yzT,
                                             unsigned short* __restrict__ yzh,
                                             unsigned short* __restrict__ yzl) {
    __shared__ float t[64][65];
    int b = blockIdx.z;
    int t0 = blockIdx.x * 64;
    int e0 = blockIdx.y * 64;
    int tid = threadIdx.x;
    for (int idx = tid; idx < 4096; idx += 256) {
        int e2 = idx >> 6, t2 = idx & 63;
        t[e2][t2] = yzT[((size_t)b * E_ + e0 + e2) * L_ + t0 + t2];
    }
    __syncthreads();
    for (int idx = tid; idx < 4096; idx += 256) {
        int t2 = idx >> 6, e2 = idx & 63;
        float v = t[e2][t2];
        unsigned short hh = f2bf(v);
        size_t o = (size_t)(b * L_ + t0 + t2) * E_ + e0 + e2;
        yzh[o] = hh;
        yzl[o] = f2bf(v - bf2f(hh));
    }
}

// ---------------- head: hrel = relu(cls @ top_w + top_b) ----------------
__global__ __launch_bounds__(256) void k_top(const float* __restrict__ cls,
                                             const float* __restrict__ w,
                                             const float* __restrict__ bias,
                                             float* __restrict__ hrel) {
    __shared__ float xs[B_][DM];
    __shared__ float red[4][64][B_];
    int tid = threadIdx.x;
    for (int c = tid; c < B_ * DM; c += 256) ((float*)xs)[c] = cls[c];
    __syncthreads();
    int jl = tid & 63;
    int kq = tid >> 6;
    int j = blockIdx.x * 64 + jl;
    float acc[B_] = {};
    for (int k = kq * (DM / 4); k < (kq + 1) * (DM / 4); ++k) {
        float wv = w[(size_t)k * H_ + j];
#pragma unroll
        for (int b = 0; b < B_; ++b) acc[b] += xs[b][k] * wv;
    }
#pragma unroll
    for (int b = 0; b < B_; ++b) red[kq][jl][b] = acc[b];
    __syncthreads();
    if (kq == 0) {
        float bv = bias[j];
#pragma unroll
        for (int b = 0; b < B_; ++b) {
            float s = red[0][jl][b] + red[1][jl][b] + red[2][jl][b] + red[3][jl][b] + bv;
            hrel[(size_t)b * H_ + j] = fmaxf(s, 0.0f);
        }
    }
}

// ---------------- head: out = hrel @ bot_w + bot_b ----------------
__global__ __launch_bounds__(256) void k_bot(const float* __restrict__ hrel,
                                             const float* __restrict__ w,
                                             const float* __restrict__ bias,
                                             float* __restrict__ out) {
    __shared__ float red[8][T_];
    int b = blockIdx.x;
    int jl = threadIdx.x & 31;
    int kq = threadIdx.x >> 5;
    if (jl < T_) {
        float acc = 0.0f;
        for (int k = kq * (H_ / 8); k < (kq + 1) * (H_ / 8); ++k)
            acc += hrel[(size_t)b * H_ + k] * w[(size_t)k * T_ + jl];
        red[kq][jl] = acc;
    }
    __syncthreads();
    if (kq == 0 && jl < T_) {
        float s = bias[jl];
#pragma unroll
        for (int q = 0; q < 8; ++q) s += red[q][jl];
        out[(size_t)b * T_ + jl] = s;
    }
}

extern "C" void kernel_launch(void* const* d_in, const int* in_sizes, int n_in,
                              void* d_out, int out_size, void* d_ws, size_t ws_size,
                              hipStream_t stream) {
    const int*   ids       = (const int*)d_in[0];
    const float* embed     = (const float*)d_in[1];
    const float* in_proj_w = (const float*)d_in[2];
    const float* conv_w    = (const float*)d_in[3];
    const float* conv_b    = (const float*)d_in[4];
    const float* x_proj_w  = (const float*)d_in[5];
    const float* dt_w      = (const float*)d_in[6];
    const float* dt_b      = (const float*)d_in[7];
    const float* A_log     = (const float*)d_in[8];
    const float* D_p       = (const float*)d_in[9];
    const float* out_w     = (const float*)d_in[10];
    const float* norm_w    = (const float*)d_in[11];
    const float* norm_f_w  = (const float*)d_in[12];
    const float* top_w     = (const float*)d_in[13];
    const float* top_b     = (const float*)d_in[14];
    const float* bot_w     = (const float*)d_in[15];
    const float* bot_b     = (const float*)d_in[16];
    float* out = (float*)d_out;

    // workspace layout
    float* ws = (float*)d_ws;
    float* h    = ws;                         // 2048*768
    float* xz   = h + (size_t)BT_ * DM;       // 2048*3072
    float* xc   = xz + (size_t)BT_ * 2 * E_;  // 2048*1536
    float* proj = xc + (size_t)BT_ * E_;      // 2048*80
    float* dtT  = proj + (size_t)BT_ * PJ;    // 2048*1536 ([b][e][t])
    float* dxT  = dtT + (size_t)BT_ * E_;     // also reused as yzT (aliased on purpose)
    float* xdT  = dxT + (size_t)BT_ * E_;
    float* zsT  = xdT + (size_t)BT_ * E_;
    float* cls  = zsT + (size_t)BT_ * E_;     // 4*768
    float* hrel = cls + (size_t)B_ * DM;      // 4*1536
    unsigned short* us = (unsigned short*)(hrel + (size_t)B_ * H_);
    unsigned short* xi_h = us;                              // 2048*768
    unsigned short* xi_l = xi_h + (size_t)BT_ * DM;
    unsigned short* yz_h = xi_l + (size_t)BT_ * DM;         // 2048*1536
    unsigned short* yz_l = yz_h + (size_t)BT_ * E_;
    unsigned short* wA_h = yz_l + (size_t)BT_ * E_;         // 3072*768
    unsigned short* wA_l = wA_h + (size_t)(2 * E_) * DM;
    unsigned short* wB_h = wA_l + (size_t)(2 * E_) * DM;    // 768*1536
    unsigned short* wB_l = wB_h + (size_t)DM * E_;
    unsigned short* xc_h = wB_l + (size_t)DM * E_;          // 2048*1536
    unsigned short* xc_l = xc_h + (size_t)BT_ * E_;
    unsigned short* wX_h = xc_l + (size_t)BT_ * E_;         // 80*1536
    unsigned short* wX_l = wX_h + (size_t)PJ * E_;
    float* pp = (float*)(wX_l + (size_t)PJ * E_);           // 4*2048*80 partials
    float* yzT = dxT;   // alias: safe (see k_scan2 comment)

    k_embed<<<BT_, 256, 0, stream>>>(ids, embed, h);

    for (int i = 0; i < NL_; ++i) {
        const float* ipw = in_proj_w + (size_t)i * DM * 2 * E_;
        const float* cwi = conv_w + (size_t)i * E_ * K_;
        const float* cbi = conv_b + (size_t)i * E_;
        const float* xpw = x_proj_w + (size_t)i * E_ * PJ;
        const float* dwi = dt_w + (size_t)i * R_ * E_;
        const float* dbi = dt_b + (size_t)i * E_;
        const float* ali = A_log + (size_t)i * E_ * N_;
        const float* dpi = D_p + (size_t)i * E_;
        const float* owi = out_w + (size_t)i * E_ * DM;
        const float* nwi = norm_w + (size_t)i * DM;

        k_rmsnorm<true><<<BT_, 256, 0, stream>>>(h, DM, nwi, nullptr, xi_h, xi_l);
        k_wsplit<<<dim3(2 * E_ / 32, DM / 32), 256, 0, stream>>>(ipw, wA_h, wA_l, DM, 2 * E_);
        // xz = xi @ in_proj (MFMA bf16x2): 128x128 tile, 2x2 waves
        k_mmf<128, 128, 2, 2, false, 1><<<dim3(2 * E_ / 128, BT_ / 128), 256, 0, stream>>>(
            xi_h, xi_l, wA_h, wA_l, xz, BT_, 2 * E_, DM);
        k_conv<<<BT_ * E_ / 256, 256, 0, stream>>>(xz, cwi, cbi, xc, xc_h, xc_l);
        // x_proj: proj[2048][80] = xc @ wX^T, K-split 4 + reduce
        k_wsplitX<<<E_ / 16, 256, 0, stream>>>(xpw, wX_h, wX_l);
        k_mmf<128, PJ, 4, 1, false, 4><<<dim3(1, BT_ / 128, 4), 256, 0, stream>>>(
            xc_h, xc_l, wX_h, wX_l, pp, BT_, PJ, E_);
        k_padd<<<(BT_ * PJ + 255) / 256, 256, 0, stream>>>(pp, proj);
        k_prep<<<dim3(L_ / 64, E_ / 64, B_), 256, 0, stream>>>(
            proj, dwi, dbi, xc, xz, dpi, dtT, dxT, xdT, zsT);
        k_scan2<<<B_ * E_, 256, 0, stream>>>(dtT, dxT, xdT, zsT, proj, ali, yzT);
        k_ytr<<<dim3(L_ / 64, E_ / 64, B_), 256, 0, stream>>>(yzT, yz_h, yz_l);
        k_wsplit<<<dim3(DM / 32, E_ / 32), 256, 0, stream>>>(owi, wB_h, wB_l, E_, DM);
        // h += yz @ out_w: 64x64 tile, 2x2 waves
        k_mmf<64, 64, 2, 2, true, 1><<<dim3(DM / 64, BT_ / 64), 256, 0, stream>>>(
            yz_h, yz_l, wB_h, wB_l, h, BT_, DM, E_);
    }

    k_rmsnorm<false><<<B_, 256, 0, stream>>>(h + (size_t)(L_ - 1) * DM, (long)L_ * DM,
                                             norm_f_w, cls, nullptr, nullptr);
    k_top<<<H_ / 64, 256, 0, stream>>>(cls, top_w, top_b, hrel);
    k_bot<<<B_, 256, 0, stream>>>(hrel, bot_w, bot_b, out);
}

// Round 9
// 1283.074 us; speedup vs baseline: 2.8034x; 1.1828x over previous
//
#include <hip/hip_runtime.h>
#include <hip/hip_bf16.h>
#include <math.h>

// Problem constants
#define B_ 4
#define L_ 512
#define DM 768
#define E_ 1536
#define N_ 16
#define R_ 48
#define K_ 4
#define NL_ 4
#define H_ 1536
#define T_ 28
#define BT_ (B_ * L_)   // 2048 tokens
#define PJ 80           // R_ + 2*N_

typedef __bf16 bf16x8 __attribute__((ext_vector_type(8)));
typedef float  f32x4  __attribute__((ext_vector_type(4)));

__device__ __forceinline__ float sigmoidf_(float v) { return 1.0f / (1.0f + expf(-v)); }
__device__ __forceinline__ float siluf_(float v) { return v * sigmoidf_(v); }
__device__ __forceinline__ float softplusf_(float v) {
    return fmaxf(v, 0.0f) + log1pf(expf(-fabsf(v)));
}
__device__ __forceinline__ unsigned short f2bf(float x) {
    unsigned u = __float_as_uint(x);
    u = u + 0x7fffu + ((u >> 16) & 1u);
    return (unsigned short)(u >> 16);
}
__device__ __forceinline__ float bf2f(unsigned short h) {
    return __uint_as_float(((unsigned)h) << 16);
}
__device__ __forceinline__ void gl_lds16(const void* g, void* l) {
    auto gp = reinterpret_cast<const __attribute__((address_space(1))) unsigned int*>(
        reinterpret_cast<uintptr_t>(g));
    auto lp = reinterpret_cast<__attribute__((address_space(3))) unsigned int*>(
        reinterpret_cast<uintptr_t>(l));
    __builtin_amdgcn_global_load_lds(gp, lp, 16, 0, 0);
}

// ---------------- embed gather ----------------
__global__ __launch_bounds__(256) void k_embed(const int* __restrict__ ids,
                                               const float* __restrict__ embed,
                                               float* __restrict__ h) {
    int bt = blockIdx.x;
    int tok = ids[bt];
    const float* src = embed + (size_t)tok * DM;
    float* dst = h + (size_t)bt * DM;
    for (int c = threadIdx.x; c < DM; c += 256) dst[c] = src[c];
}

// ---------------- RMSNorm; BF=true emits bf16 hi/lo split ----------------
template <bool BF>
__global__ __launch_bounds__(256) void k_rmsnorm(const float* __restrict__ base, long rstride,
                                                 const float* __restrict__ w,
                                                 float* __restrict__ outf,
                                                 unsigned short* __restrict__ oh,
                                                 unsigned short* __restrict__ ol) {
    int tid = threadIdx.x;
    const float* row = base + (size_t)blockIdx.x * rstride;
    float v0 = row[tid], v1 = row[tid + 256], v2 = row[tid + 512];
    float s = v0 * v0 + v1 * v1 + v2 * v2;
#pragma unroll
    for (int m = 1; m < 64; m <<= 1) s += __shfl_xor(s, m);
    __shared__ float red[4];
    if ((tid & 63) == 0) red[tid >> 6] = s;
    __syncthreads();
    s = red[0] + red[1] + red[2] + red[3];
    float rs = rsqrtf(s * (1.0f / (float)DM) + 1e-5f);
    float r0 = v0 * rs * w[tid];
    float r1 = v1 * rs * w[tid + 256];
    float r2 = v2 * rs * w[tid + 512];
    size_t o = (size_t)blockIdx.x * DM;
    if (BF) {
        unsigned short h0 = f2bf(r0), h1 = f2bf(r1), h2 = f2bf(r2);
        oh[o + tid] = h0;        ol[o + tid] = f2bf(r0 - bf2f(h0));
        oh[o + tid + 256] = h1;  ol[o + tid + 256] = f2bf(r1 - bf2f(h1));
        oh[o + tid + 512] = h2;  ol[o + tid + 512] = f2bf(r2 - bf2f(h2));
    } else {
        outf[o + tid] = r0;
        outf[o + tid + 256] = r1;
        outf[o + tid + 512] = r2;
    }
}

// ---------------- weight transpose + split: w[K][N] -> wT_hi/lo[N][K] (32x32 tiles) -----------
__global__ __launch_bounds__(256) void k_wsplit(const float* __restrict__ w,
                                                unsigned short* __restrict__ th,
                                                unsigned short* __restrict__ tl,
                                                int K, int N) {
    __shared__ float t[32][33];
    int n0 = blockIdx.x * 32, k0 = blockIdx.y * 32;
    int c = threadIdx.x & 31, r0 = threadIdx.x >> 5;
#pragma unroll
    for (int it = 0; it < 4; ++it) {
        int r = r0 + it * 8;
        t[r][c] = w[(size_t)(k0 + r) * N + n0 + c];
    }
    __syncthreads();
#pragma unroll
    for (int it = 0; it < 4; ++it) {
        int r = r0 + it * 8;
        float v = t[c][r];
        unsigned short h = f2bf(v);
        th[(size_t)(n0 + r) * K + k0 + c] = h;
        tl[(size_t)(n0 + r) * K + k0 + c] = f2bf(v - bf2f(h));
    }
}

// ---------------- x_proj weight: w[1536][80] -> wX_hi/lo[80][1536] ----------------
__global__ __launch_bounds__(256) void k_wsplitX(const float* __restrict__ w,
                                                 unsigned short* __restrict__ th,
                                                 unsigned short* __restrict__ tl) {
    __shared__ float t[16][PJ];
    int k0 = blockIdx.x * 16;
    for (int i = threadIdx.x; i < 16 * PJ; i += 256)
        t[i / PJ][i % PJ] = w[(size_t)(k0 + i / PJ) * PJ + i % PJ];
    __syncthreads();
    for (int i = threadIdx.x; i < 16 * PJ; i += 256) {
        int j = i >> 4, kk = i & 15;     // j<80, kk<16
        float v = t[kk][j];
        unsigned short h = f2bf(v);
        th[(size_t)j * E_ + k0 + kk] = h;
        tl[(size_t)j * E_ + k0 + kk] = f2bf(v - bf2f(h));
    }
}

// ---------------- MFMA GEMM (bf16x2 split): C (+)= A[M,K] @ BT[N,K]^T ----------------
// 256 threads = 4 waves arranged WR x WC; wave tile (BM/WR) x (BN/WC); K-step 32.
// KS>1: grid.z splits K; block kz writes partial C at C + kz*M*N (ACCUM must be false).
template <int BM, int BN, int WR, int WC, bool ACCUM, int KS>
__global__ __launch_bounds__(256) void k_mmf(const unsigned short* __restrict__ Ah,
                                             const unsigned short* __restrict__ Al,
                                             const unsigned short* __restrict__ Bh,
                                             const unsigned short* __restrict__ Bl,
                                             float* __restrict__ C,
                                             int M, int N, int K) {
    constexpr int WM = BM / WR, WN = BN / WC;
    constexpr int MR = WM / 16, NR = WN / 16;
    constexpr int CA = 4 * BM, CB = 4 * BN;
    constexpr int RA = (CA + 255) / 256, RB = (CB + 255) / 256;
    __shared__ __align__(16) unsigned short sAh[CA * 8], sAl[CA * 8];
    __shared__ __align__(16) unsigned short sBh[CB * 8], sBl[CB * 8];
    int tid = threadIdx.x;
    int lane = tid & 63;
    int w = tid >> 6;
    int wr = w / WC, wc = w % WC;
    int m0 = blockIdx.y * BM, n0 = blockIdx.x * BN;
    int kz = (KS > 1) ? blockIdx.z : 0;
    int kb = kz * (K / KS), ke = kb + K / KS;

    f32x4 acc[MR][NR] = {};

    for (int k0 = kb; k0 < ke; k0 += 32) {
#pragma unroll
        for (int r = 0; r < RA; ++r) {
            int cell = (r * 4 + w) * 64 + lane;
            if (CA % 256 == 0 || cell < CA) {
                int oct = cell / BM, row = cell % BM;
                size_t go = (size_t)(m0 + row) * K + k0 + oct * 8;
                gl_lds16(Ah + go, &sAh[(size_t)cell * 8]);
                gl_lds16(Al + go, &sAl[(size_t)cell * 8]);
            }
        }
#pragma unroll
        for (int r = 0; r < RB; ++r) {
            int cell = (r * 4 + w) * 64 + lane;
            if (CB % 256 == 0 || cell < CB) {
                int oct = cell / BN, row = cell % BN;
                size_t go = (size_t)(n0 + row) * K + k0 + oct * 8;
                gl_lds16(Bh + go, &sBh[(size_t)cell * 8]);
                gl_lds16(Bl + go, &sBl[(size_t)cell * 8]);
            }
        }
        asm volatile("s_waitcnt vmcnt(0)" ::: "memory");
        __syncthreads();

        int oct = lane >> 4;
        int rl = lane & 15;
        bf16x8 ah[MR], al[MR], bh[NR], bl[NR];
#pragma unroll
        for (int i = 0; i < MR; ++i) {
            int row = wr * WM + i * 16 + rl;
            ah[i] = *(const bf16x8*)&sAh[(oct * BM + row) * 8];
            al[i] = *(const bf16x8*)&sAl[(oct * BM + row) * 8];
        }
#pragma unroll
        for (int j = 0; j < NR; ++j) {
            int row = wc * WN + j * 16 + rl;
            bh[j] = *(const bf16x8*)&sBh[(oct * BN + row) * 8];
            bl[j] = *(const bf16x8*)&sBl[(oct * BN + row) * 8];
        }
#pragma unroll
        for (int i = 0; i < MR; ++i)
#pragma unroll
            for (int j = 0; j < NR; ++j) {
                acc[i][j] = __builtin_amdgcn_mfma_f32_16x16x32_bf16(ah[i], bh[j], acc[i][j], 0, 0, 0);
                acc[i][j] = __builtin_amdgcn_mfma_f32_16x16x32_bf16(ah[i], bl[j], acc[i][j], 0, 0, 0);
                acc[i][j] = __builtin_amdgcn_mfma_f32_16x16x32_bf16(al[i], bh[j], acc[i][j], 0, 0, 0);
            }
        __syncthreads();
    }
    float* Cw = C + (size_t)kz * M * N;
    int rl = lane & 15, rq = lane >> 4;
#pragma unroll
    for (int i = 0; i < MR; ++i)
#pragma unroll
        for (int j = 0; j < NR; ++j)
#pragma unroll
            for (int v = 0; v < 4; ++v) {
                int row = m0 + wr * WM + i * 16 + rq * 4 + v;
                int col = n0 + wc * WN + j * 16 + rl;
                float val = acc[i][j][v];
                if (ACCUM) val += Cw[(size_t)row * N + col];
                Cw[(size_t)row * N + col] = val;
            }
}

// ---------------- K-split partial reduce: proj = sum_{kz} pp[kz] ----------------
__global__ __launch_bounds__(256) void k_padd(const float* __restrict__ pp,
                                              float* __restrict__ proj) {
    int idx = blockIdx.x * 256 + threadIdx.x;
    const int MN = BT_ * PJ;
    if (idx < MN)
        proj[idx] = pp[idx] + pp[MN + idx] + pp[2 * MN + idx] + pp[3 * MN + idx];
}

// ---------------- causal depthwise conv (K=4) + SiLU; emits f32 + bf16 hi/lo ---------------
__global__ __launch_bounds__(256) void k_conv(const float* __restrict__ xz,
                                              const float* __restrict__ cw,
                                              const float* __restrict__ cb,
                                              float* __restrict__ xc,
                                              unsigned short* __restrict__ xch,
                                              unsigned short* __restrict__ xcl) {
    int idx = blockIdx.x * 256 + threadIdx.x;
    int e = idx % E_;
    int bt = idx / E_;
    int t = bt & (L_ - 1);
    const float* base = xz + (size_t)bt * (2 * E_) + e;
    float w0 = cw[e * 4 + 0], w1 = cw[e * 4 + 1], w2 = cw[e * 4 + 2], w3 = cw[e * 4 + 3];
    float acc = cb[e] + base[0] * w3;
    if (t >= 1) acc += base[-(2 * E_)] * w2;
    if (t >= 2) acc += base[-(4 * E_)] * w1;
    if (t >= 3) acc += base[-(6 * E_)] * w0;
    float v = siluf_(acc);
    xc[idx] = v;
    unsigned short hh = f2bf(v);
    xch[idx] = hh;
    xcl[idx] = f2bf(v - bf2f(hh));
}

// ---------------- k_prep: dt GEMM(K=48)+softplus + transposed scan inputs ----------------
__global__ __launch_bounds__(256) void k_prep(const float* __restrict__ proj,
                                              const float* __restrict__ dw,
                                              const float* __restrict__ db,
                                              const float* __restrict__ xc,
                                              const float* __restrict__ xz,
                                              const float* __restrict__ dp,
                                              float* __restrict__ dtT,
                                              float* __restrict__ dxT,
                                              float* __restrict__ xdT,
                                              float* __restrict__ zsT) {
    __shared__ float projS[64][48];
    __shared__ float dwS[48][64];
    __shared__ float tileT[64][65];
    int b = blockIdx.z;
    int t0 = blockIdx.x * 64;
    int e0 = blockIdx.y * 64;
    int tid = threadIdx.x;

    for (int idx = tid; idx < 64 * 48; idx += 256) {
        int tl = idx / 48, k = idx % 48;
        projS[tl][k] = proj[(size_t)(b * L_ + t0 + tl) * PJ + k];
    }
    for (int idx = tid; idx < 48 * 64; idx += 256) {
        int k = idx >> 6, ee = idx & 63;
        dwS[k][ee] = dw[(size_t)k * E_ + e0 + ee];
    }
    __syncthreads();

    int el = tid & 63;
    int tg = tid >> 6;
    float acc[16];
    float bvE = db[e0 + el];
#pragma unroll
    for (int s = 0; s < 16; ++s) acc[s] = bvE;
    for (int k = 0; k < 48; ++k) {
        float wv = dwS[k][el];
#pragma unroll
        for (int s = 0; s < 16; ++s) acc[s] += projS[tg * 16 + s][k] * wv;
    }
    float dtv[16];
#pragma unroll
    for (int s = 0; s < 16; ++s) dtv[s] = softplusf_(acc[s]);
    float xv[16];
#pragma unroll
    for (int s = 0; s < 16; ++s)
        xv[s] = xc[(size_t)(b * L_ + t0 + tg * 16 + s) * E_ + e0 + el];
    float dpv = dp[e0 + el];

#define XPOSE_OUT(dst, EXPR)                                                      \
    do {                                                                          \
        __syncthreads();                                                          \
        for (int s = 0; s < 16; ++s) tileT[el][tg * 16 + s] = (EXPR);             \
        __syncthreads();                                                          \
        for (int idx = tid; idx < 4096; idx += 256) {                             \
            int e2 = idx >> 6, t2 = idx & 63;                                     \
            dst[((size_t)b * E_ + e0 + e2) * L_ + t0 + t2] = tileT[e2][t2];       \
        }                                                                         \
    } while (0)

    XPOSE_OUT(dtT, dtv[s]);
    XPOSE_OUT(dxT, dtv[s] * xv[s]);
    XPOSE_OUT(xdT, xv[s] * dpv);
    float zv[16];
#pragma unroll
    for (int s = 0; s < 16; ++s)
        zv[s] = xz[(size_t)(b * L_ + t0 + tg * 16 + s) * (2 * E_) + E_ + e0 + el];
    XPOSE_OUT(zsT, siluf_(zv[s]));
#undef XPOSE_OUT
}

// ---------------- chunked parallel selective scan v3 -> yzT f32 [b][e][t] ----------------
// 256 thr = 16 chunks x 16 n; 32 t per chunk. No input staging (global reads are
// broadcast/L2-resident). Phase 2 writes p=h*C to LDS (off critical path) instead of
// 4 serial shuffles; reduce pass sums 16 floats/t via conflict-free pad-20 b128 reads.
// yzT may alias dxT (all dxT reads in phase 1 finish before first output write).
__global__ __launch_bounds__(256) void k_scan3(const float* __restrict__ dtT,
                                               const float* dxT,
                                               const float* __restrict__ xdT,
                                               const float* __restrict__ zsT,
                                               const float* __restrict__ proj,
                                               const float* __restrict__ A_log,
                                               float* yzT) {
    __shared__ float s_p[16 * 16 * 20];            // [c][s'][20] pad-20
    __shared__ float sAP[16][17], sAS[16][17], sH[16][17];
    int tid = threadIdx.x;
    int b = blockIdx.x / E_;
    int e = blockIdx.x - b * E_;
    size_t base = ((size_t)b * E_ + e) * L_;

    int c = tid >> 4;
    int n = tid & 15;
    float A = -expf(A_log[e * N_ + n]);

    int t0 = c * 32;
    const float* pdt = dtT + base + t0;
    const float* pdx = dxT + base + t0;
    const float* pb = proj + (size_t)(b * L_ + t0) * PJ + R_ + n;
    const float* pc = pb + N_;

    // phase 1: per-chunk (P, S); cache dA,u in registers
    float dAr[32], ur[32];
    float P = 1.0f, S = 0.0f;
#pragma unroll
    for (int s = 0; s < 32; ++s) {
        float dA = expf(pdt[s] * A);
        float u = pdx[s] * pb[s * PJ];
        dAr[s] = dA;
        ur[s] = u;
        P *= dA;
        S = dA * S + u;
    }
    sAP[c][n] = P;
    sAS[c][n] = S;
    __syncthreads();
    if (tid < 16) {
        float Hc = 0.0f;
        for (int c2 = 0; c2 < 16; ++c2) {
            sH[c2][tid] = Hc;
            Hc = sAP[c2][tid] * Hc + sAS[c2][tid];
        }
    }
    __syncthreads();

    float h = sH[c][n];
    float* myrow = &s_p[(c * 16) * 20 + n];
    // ---- half 1: s = 0..15 ----
#pragma unroll
    for (int s = 0; s < 16; ++s) {
        h = dAr[s] * h + ur[s];
        myrow[s * 20] = h * pc[s * PJ];
    }
    __syncthreads();
    {
        int rc = tid >> 4, rs = tid & 15;          // (chunk, s')
        const float* row = &s_p[(rc * 16 + rs) * 20];
        f32x4 v0 = *(const f32x4*)&row[0];
        f32x4 v1 = *(const f32x4*)&row[4];
        f32x4 v2 = *(const f32x4*)&row[8];
        f32x4 v3 = *(const f32x4*)&row[12];
        float sum = (v0[0]+v0[1]+v0[2]+v0[3]) + (v1[0]+v1[1]+v1[2]+v1[3]) +
                    (v2[0]+v2[1]+v2[2]+v2[3]) + (v3[0]+v3[1]+v3[2]+v3[3]);
        int t = rc * 32 + rs;
        yzT[base + t] = (sum + xdT[base + t]) * zsT[base + t];
    }
    __syncthreads();
    // ---- half 2: s = 16..31 ----
#pragma unroll
    for (int s = 0; s < 16; ++s) {
        h = dAr[16 + s] * h + ur[16 + s];
        myrow[s * 20] = h * pc[(16 + s) * PJ];
    }
    __syncthreads();
    {
        int rc = tid >> 4, rs = tid & 15;
        const float* row = &s_p[(rc * 16 + rs) * 20];
        f32x4 v0 = *(const f32x4*)&row[0];
        f32x4 v1 = *(const f32x4*)&row[4];
        f32x4 v2 = *(const f32x4*)&row[8];
        f32x4 v3 = *(const f32x4*)&row[12];
        float sum = (v0[0]+v0[1]+v0[2]+v0[3]) + (v1[0]+v1[1]+v1[2]+v1[3]) +
                    (v2[0]+v2[1]+v2[2]+v2[3]) + (v3[0]+v3[1]+v3[2]+v3[3]);
        int t = rc * 32 + 16 + rs;
        yzT[base + t] = (sum + xdT[base + t]) * zsT[base + t];
    }
}

// ---------------- yzT [b][e][t] f32 -> yz_h/yz_l [bt][e] bf16 (64x64 LDS transpose) --------
__global__ __launch_bounds__(256) void k_ytr(const float* __restrict__ yzT,
                                             unsigned short* __restrict__ yzh,
                                             unsigned short* __restrict__ yzl) {
    __shared__ float t[64][65];
    int b = blockIdx.z;
    int t0 = blockIdx.x * 64;
    int e0 = blockIdx.y * 64;
    int tid = threadIdx.x;
    for (int idx = tid; idx < 4096; idx += 256) {
        int e2 = idx >> 6, t2 = idx & 63;
        t[e2][t2] = yzT[((size_t)b * E_ + e0 + e2) * L_ + t0 + t2];
    }
    __syncthreads();
    for (int idx = tid; idx < 4096; idx += 256) {
        int t2 = idx >> 6, e2 = idx & 63;
        float v = t[e2][t2];
        unsigned short hh = f2bf(v);
        size_t o = (size_t)(b * L_ + t0 + t2) * E_ + e0 + e2;
        yzh[o] = hh;
        yzl[o] = f2bf(v - bf2f(hh));
    }
}

// ---------------- head: hrel = relu(cls @ top_w + top_b) ----------------
__global__ __launch_bounds__(256) void k_top(const float* __restrict__ cls,
                                             const float* __restrict__ w,
                                             const float* __restrict__ bias,
                                             float* __restrict__ hrel) {
    __shared__ float xs[B_][DM];
    __shared__ float red[4][64][B_];
    int tid = threadIdx.x;
    for (int c = tid; c < B_ * DM; c += 256) ((float*)xs)[c] = cls[c];
    __syncthreads();
    int jl = tid & 63;
    int kq = tid >> 6;
    int j = blockIdx.x * 64 + jl;
    float acc[B_] = {};
    for (int k = kq * (DM / 4); k < (kq + 1) * (DM / 4); ++k) {
        float wv = w[(size_t)k * H_ + j];
#pragma unroll
        for (int b = 0; b < B_; ++b) acc[b] += xs[b][k] * wv;
    }
#pragma unroll
    for (int b = 0; b < B_; ++b) red[kq][jl][b] = acc[b];
    __syncthreads();
    if (kq == 0) {
        float bv = bias[j];
#pragma unroll
        for (int b = 0; b < B_; ++b) {
            float s = red[0][jl][b] + red[1][jl][b] + red[2][jl][b] + red[3][jl][b] + bv;
            hrel[(size_t)b * H_ + j] = fmaxf(s, 0.0f);
        }
    }
}

// ---------------- head: out = hrel @ bot_w + bot_b ----------------
__global__ __launch_bounds__(256) void k_bot(const float* __restrict__ hrel,
                                             const float* __restrict__ w,
                                             const float* __restrict__ bias,
                                             float* __restrict__ out) {
    __shared__ float red[8][T_];
    int b = blockIdx.x;
    int jl = threadIdx.x & 31;
    int kq = threadIdx.x >> 5;
    if (jl < T_) {
        float acc = 0.0f;
        for (int k = kq * (H_ / 8); k < (kq + 1) * (H_ / 8); ++k)
            acc += hrel[(size_t)b * H_ + k] * w[(size_t)k * T_ + jl];
        red[kq][jl] = acc;
    }
    __syncthreads();
    if (kq == 0 && jl < T_) {
        float s = bias[jl];
#pragma unroll
        for (int q = 0; q < 8; ++q) s += red[q][jl];
        out[(size_t)b * T_ + jl] = s;
    }
}

extern "C" void kernel_launch(void* const* d_in, const int* in_sizes, int n_in,
                              void* d_out, int out_size, void* d_ws, size_t ws_size,
                              hipStream_t stream) {
    const int*   ids       = (const int*)d_in[0];
    const float* embed     = (const float*)d_in[1];
    const float* in_proj_w = (const float*)d_in[2];
    const float* conv_w    = (const float*)d_in[3];
    const float* conv_b    = (const float*)d_in[4];
    const float* x_proj_w  = (const float*)d_in[5];
    const float* dt_w      = (const float*)d_in[6];
    const float* dt_b      = (const float*)d_in[7];
    const float* A_log     = (const float*)d_in[8];
    const float* D_p       = (const float*)d_in[9];
    const float* out_w     = (const float*)d_in[10];
    const float* norm_w    = (const float*)d_in[11];
    const float* norm_f_w  = (const float*)d_in[12];
    const float* top_w     = (const float*)d_in[13];
    const float* top_b     = (const float*)d_in[14];
    const float* bot_w     = (const float*)d_in[15];
    const float* bot_b     = (const float*)d_in[16];
    float* out = (float*)d_out;

    // workspace layout
    float* ws = (float*)d_ws;
    float* h    = ws;                         // 2048*768
    float* xz   = h + (size_t)BT_ * DM;       // 2048*3072
    float* xc   = xz + (size_t)BT_ * 2 * E_;  // 2048*1536
    float* proj = xc + (size_t)BT_ * E_;      // 2048*80
    float* dtT  = proj + (size_t)BT_ * PJ;    // 2048*1536 ([b][e][t])
    float* dxT  = dtT + (size_t)BT_ * E_;     // also reused as yzT (aliased on purpose)
    float* xdT  = dxT + (size_t)BT_ * E_;
    float* zsT  = xdT + (size_t)BT_ * E_;
    float* cls  = zsT + (size_t)BT_ * E_;     // 4*768
    float* hrel = cls + (size_t)B_ * DM;      // 4*1536
    unsigned short* us = (unsigned short*)(hrel + (size_t)B_ * H_);
    unsigned short* xi_h = us;                              // 2048*768
    unsigned short* xi_l = xi_h + (size_t)BT_ * DM;
    unsigned short* yz_h = xi_l + (size_t)BT_ * DM;         // 2048*1536
    unsigned short* yz_l = yz_h + (size_t)BT_ * E_;
    unsigned short* wA_h = yz_l + (size_t)BT_ * E_;         // 3072*768
    unsigned short* wA_l = wA_h + (size_t)(2 * E_) * DM;
    unsigned short* wB_h = wA_l + (size_t)(2 * E_) * DM;    // 768*1536
    unsigned short* wB_l = wB_h + (size_t)DM * E_;
    unsigned short* xc_h = wB_l + (size_t)DM * E_;          // 2048*1536
    unsigned short* xc_l = xc_h + (size_t)BT_ * E_;
    unsigned short* wX_h = xc_l + (size_t)BT_ * E_;         // 80*1536
    unsigned short* wX_l = wX_h + (size_t)PJ * E_;
    float* pp = (float*)(wX_l + (size_t)PJ * E_);           // 4*2048*80 partials
    float* yzT = dxT;   // alias: safe (see k_scan3 comment)

    k_embed<<<BT_, 256, 0, stream>>>(ids, embed, h);

    for (int i = 0; i < NL_; ++i) {
        const float* ipw = in_proj_w + (size_t)i * DM * 2 * E_;
        const float* cwi = conv_w + (size_t)i * E_ * K_;
        const float* cbi = conv_b + (size_t)i * E_;
        const float* xpw = x_proj_w + (size_t)i * E_ * PJ;
        const float* dwi = dt_w + (size_t)i * R_ * E_;
        const float* dbi = dt_b + (size_t)i * E_;
        const float* ali = A_log + (size_t)i * E_ * N_;
        const float* dpi = D_p + (size_t)i * E_;
        const float* owi = out_w + (size_t)i * E_ * DM;
        const float* nwi = norm_w + (size_t)i * DM;

        k_rmsnorm<true><<<BT_, 256, 0, stream>>>(h, DM, nwi, nullptr, xi_h, xi_l);
        k_wsplit<<<dim3(2 * E_ / 32, DM / 32), 256, 0, stream>>>(ipw, wA_h, wA_l, DM, 2 * E_);
        // xz = xi @ in_proj (MFMA bf16x2): 128x128 tile, 2x2 waves
        k_mmf<128, 128, 2, 2, false, 1><<<dim3(2 * E_ / 128, BT_ / 128), 256, 0, stream>>>(
            xi_h, xi_l, wA_h, wA_l, xz, BT_, 2 * E_, DM);
        k_conv<<<BT_ * E_ / 256, 256, 0, stream>>>(xz, cwi, cbi, xc, xc_h, xc_l);
        // x_proj: proj[2048][80] = xc @ wX^T, K-split 4 + reduce
        k_wsplitX<<<E_ / 16, 256, 0, stream>>>(xpw, wX_h, wX_l);
        k_mmf<128, PJ, 4, 1, false, 4><<<dim3(1, BT_ / 128, 4), 256, 0, stream>>>(
            xc_h, xc_l, wX_h, wX_l, pp, BT_, PJ, E_);
        k_padd<<<(BT_ * PJ + 255) / 256, 256, 0, stream>>>(pp, proj);
        k_prep<<<dim3(L_ / 64, E_ / 64, B_), 256, 0, stream>>>(
            proj, dwi, dbi, xc, xz, dpi, dtT, dxT, xdT, zsT);
        k_scan3<<<B_ * E_, 256, 0, stream>>>(dtT, dxT, xdT, zsT, proj, ali, yzT);
        k_ytr<<<dim3(L_ / 64, E_ / 64, B_), 256, 0, stream>>>(yzT, yz_h, yz_l);
        k_wsplit<<<dim3(DM / 32, E_ / 32), 256, 0, stream>>>(owi, wB_h, wB_l, E_, DM);
        // h += yz @ out_w: 64x64 tile, 2x2 waves
        k_mmf<64, 64, 2, 2, true, 1><<<dim3(DM / 64, BT_ / 64), 256, 0, stream>>>(
            yz_h, yz_l, wB_h, wB_l, h, BT_, DM, E_);
    }

    k_rmsnorm<false><<<B_, 256, 0, stream>>>(h + (size_t)(L_ - 1) * DM, (long)L_ * DM,
                                             norm_f_w, cls, nullptr, nullptr);
    k_top<<<H_ / 64, 256, 0, stream>>>(cls, top_w, top_b, hrel);
    k_bot<<<B_, 256, 0, stream>>>(hrel, bot_w, bot_b, out);
}